// Round 11
// baseline (75.353 us; speedup 1.0000x reference)
//
#include <hip/hip_runtime.h>
#include <math.h>

#define LQ 4096
#define DD 512
#define NH 8
#define HS 64
#define HALF 32

typedef unsigned short u16;
typedef unsigned int u32;
typedef __attribute__((ext_vector_type(8)))  short s8v;   // 8 x bf16 (MFMA A/B frag)
typedef __attribute__((ext_vector_type(4)))  float f4v;
typedef __attribute__((ext_vector_type(4)))  u32  u32x4;
typedef __attribute__((ext_vector_type(16))) float f16v;  // 32x32 MFMA C/D

// workspace offsets (in floats)
#define WS_QH   0u
#define WS_KH   2097152u
#define WS_KL   3145728u    // unused
#define WS_VT   4194304u
#define WS_XFH  5242880u    // frag-packed X (bf16); later A_state spans XFH+XFL; later Gf
#define WS_XFL  6291456u
#define WS_WF   7340032u    // frag-packed W bf16
#define WS_GATE 8650752u    // gate bf16
#define WS_TAB  10747904u
#define WS_KTWH 11272192u   // ktw; later St

__device__ inline u16 f2bf(float x) {
    unsigned int u = __float_as_uint(x);
    return (u16)((u + 0x7fffu + ((u >> 16) & 1u)) >> 16);
}
__device__ inline float bf2f(u16 h) { return __uint_as_float(((unsigned int)h) << 16); }

__device__ __forceinline__ void gld16(void* lds, const void* g) {
    __builtin_amdgcn_global_load_lds(
        (const __attribute__((address_space(1))) void*)g,
        (__attribute__((address_space(3))) void*)lds, 16, 0, 0);
}

// ---------------- merged prep: xPos tables | X->frag bf16 | W->frag bf16 ----------------
__global__ __launch_bounds__(256) void k_pre(
    const float* __restrict__ X,
    const float* __restrict__ Wq, const float* __restrict__ Wk, const float* __restrict__ Wv,
    const float* __restrict__ Wg, const float* __restrict__ Wo,
    float* __restrict__ tab, u16* __restrict__ Xf, u16* __restrict__ Wf) {
    __shared__ float tile[32][33];
    const int b = blockIdx.x;
    const int t = threadIdx.x;
    if (b < 512) {
        int idx = b * 256 + t;
        if (idx >= LQ * HALF) return;
        int l = idx >> 5;
        int i = idx & 31;
        double log2sv = log2((2.0 * i + 25.6) / 89.6);
        double e = (double)l * log2sv * (1.0 / 512.0);
        float sc  = exp2f((float)e);
        float sci = exp2f((float)(-e));
        double invf = exp2((double)i * (-13.287712379549449 / 32.0));
        double th = (double)l * invf;
        double r = th - 6.283185307179586 * floor(th * 0.15915494309189535);
        float c = cosf((float)r), sn = sinf((float)r);
        tab[idx]                 = c * sc;
        tab[LQ*HALF + idx]       = sn * sc;
        tab[2*LQ*HALF + idx]     = c * sci;
        tab[3*LQ*HALF + idx]     = sn * sci;
    } else if (b < 1536) {
        // X -> fragment-packed bf16: Xf[rb:128][kt:8][ks:4][lane:64][8]
        int g = (b - 512) * 256 + t;
        int l = g >> 6;
        int d = (g & 63) * 8;
        const float* xp = X + (size_t)l * DD + d;
        f4v x0 = *(const f4v*)xp;
        f4v x1 = *(const f4v*)(xp + 4);
        s8v ph;
#pragma unroll
        for (int j = 0; j < 4; ++j) {
            ph[j]   = (short)f2bf(x0[j]);
            ph[j+4] = (short)f2bf(x1[j]);
        }
        int rb = l >> 5, kt = d >> 6, ks = (d >> 4) & 3, kh2 = (d >> 3) & 1;
        int lane = kh2 * 32 + (l & 31);
        size_t off = (((size_t)(rb * 8 + kt) * 4 + ks) * 64 + lane) * 8;
        *(s8v*)(Xf + off) = ph;
    } else {
        // weights -> fragment-packed bf16: Wf[nb:80][kt:8][ks:4][lane:64][8]
        int bb = b - 1536;
        int d0 = (bb & 15) * 32, C0 = (bb >> 4) * 32;
        int proj = C0 >> 9;
        int tc = t & 31, tr = t >> 5;
#pragma unroll
        for (int rr = 0; rr < 4; ++rr) {
            int dl = tr + rr * 8;
            int d = d0 + dl;
            int C = C0 + tc;
            float val;
            if (proj < 3) {
                const float* W = (proj == 0) ? Wq : ((proj == 1) ? Wk : Wv);
                int h = (C & 511) >> 6, hs = C & 63;
                val = W[(size_t)h * (DD * HS) + (size_t)d * HS + hs];
            } else if (proj == 3) {
                val = Wg[(size_t)d * DD + (C & 511)];
            } else {
                val = Wo[(size_t)d * DD + (C - 2048)];
            }
            tile[dl][tc] = val;
        }
        __syncthreads();
        if (t < 128) {
            int cl = t & 31, dgq = t >> 5;
            int dl = dgq * 8;
            s8v pk;
#pragma unroll
            for (int j = 0; j < 8; ++j) pk[j] = (short)f2bf(tile[dl + j][cl]);
            int C = C0 + cl;
            int da = d0 + dl;
            int nb = C >> 5, kt = da >> 6, ks = (da >> 4) & 3, kh2 = (da >> 3) & 1;
            int lane = kh2 * 32 + (C & 31);
            size_t off = (((size_t)(nb * 8 + kt) * 4 + ks) * 64 + lane) * 8;
            *(s8v*)(Wf + off) = pk;
        }
    }
}

// ---------------- fused MFMA GEMM: 128x128 blocks, A frag-direct pinned, B LDS 4 phases ----------------
// grid 512 (XCD-chunked swizzle), block 256 (4 waves, each 32l x 128c).
__global__ __launch_bounds__(256) void k_fused(
    const u16* __restrict__ Xf, const u16* __restrict__ Wf,
    const float* __restrict__ tab,
    u16* __restrict__ qh, u16* __restrict__ kh,
    u16* __restrict__ vt, u16* __restrict__ gate16,
    u16* __restrict__ ktw) {
    __shared__ __align__(16) char smem[33536];   // B stage 32KB [n:4][ktl:2][4KB]; vbuf alias after loop
    const int t = threadIdx.x;
    const int b = blockIdx.x;                    // 512 blocks
    const int cb = (b >> 3) & 15;                // 0..15
    const int mb = (b & 7) * 4 + (b >> 7);       // 0..31, XCD-chunked
    const int l0 = mb * 128;
    const int c0 = cb * 128;
    const int wv = t >> 6;
    const int lane = t & 63;
    const int c31 = lane & 31;
    const int hi = lane >> 5;

    const int rb = mb * 4 + wv;
    const u16* pA = Xf + (size_t)rb * 16384 + lane * 8;
    const char* gB = (const char*)(Wf + (size_t)(cb * 4) * 16384);

    f16v acc0, acc1, acc2, acc3;
#pragma unroll
    for (int i = 0; i < 16; ++i) { acc0[i] = 0.f; acc1[i] = 0.f; acc2[i] = 0.f; acc3[i] = 0.f; }

    // stage B kts {2P,2P+1} for all 4 n-subtiles: 8 x 4KB chunks (16B/thread each)
#define STAGEB(P)                                                                  \
    { _Pragma("unroll") for (int j = 0; j < 8; ++j) {                              \
        int n_ = j >> 1, kl_ = j & 1;                                              \
        gld16(smem + n_ * 8192 + kl_ * 4096 + wv * 1024,                           \
              gB + n_ * 32768 + ((P) * 2 + kl_) * 4096 + t * 16); } }
    s8v aA[4], aB[4];
#define LOADA(S, KT)                                                               \
    { _Pragma("unroll") for (int ks = 0; ks < 4; ++ks) {                           \
        a##S[ks] = *(const s8v*)(pA + (KT) * 2048 + ks * 512); } }
#define MFMAK(S, KT)                                                                           \
    { const char* bbq = smem + ((KT) & 1) * 4096;                                              \
      _Pragma("unroll") for (int ks = 0; ks < 4; ++ks) {                                       \
        s8v b0 = *(const s8v*)(bbq + 0 * 8192 + ks * 1024 + lane * 16);                        \
        s8v b1 = *(const s8v*)(bbq + 1 * 8192 + ks * 1024 + lane * 16);                        \
        s8v b2 = *(const s8v*)(bbq + 2 * 8192 + ks * 1024 + lane * 16);                        \
        s8v b3 = *(const s8v*)(bbq + 3 * 8192 + ks * 1024 + lane * 16);                        \
        acc0 = __builtin_amdgcn_mfma_f32_32x32x16_bf16(a##S[ks], b0, acc0, 0, 0, 0);           \
        acc1 = __builtin_amdgcn_mfma_f32_32x32x16_bf16(a##S[ks], b1, acc1, 0, 0, 0);           \
        acc2 = __builtin_amdgcn_mfma_f32_32x32x16_bf16(a##S[ks], b2, acc2, 0, 0, 0);           \
        acc3 = __builtin_amdgcn_mfma_f32_32x32x16_bf16(a##S[ks], b3, acc3, 0, 0, 0); } }

    LOADA(A, 0)
    STAGEB(0)
    asm volatile("s_waitcnt vmcnt(0)" ::: "memory");
    __syncthreads();
    // phase 0: kts 0,1
    LOADA(B, 1)
    __builtin_amdgcn_sched_barrier(0);
    MFMAK(A, 0)
    __builtin_amdgcn_sched_barrier(0);
    MFMAK(B, 1)
    __syncthreads();
    STAGEB(1)
    LOADA(A, 2)
    asm volatile("s_waitcnt vmcnt(0)" ::: "memory");
    __syncthreads();
    // phase 1: kts 2,3
    LOADA(B, 3)
    __builtin_amdgcn_sched_barrier(0);
    MFMAK(A, 2)
    __builtin_amdgcn_sched_barrier(0);
    MFMAK(B, 3)
    __syncthreads();
    STAGEB(2)
    LOADA(A, 4)
    asm volatile("s_waitcnt vmcnt(0)" ::: "memory");
    __syncthreads();
    // phase 2: kts 4,5
    LOADA(B, 5)
    __builtin_amdgcn_sched_barrier(0);
    MFMAK(A, 4)
    __builtin_amdgcn_sched_barrier(0);
    MFMAK(B, 5)
    __syncthreads();
    STAGEB(3)
    LOADA(A, 6)
    asm volatile("s_waitcnt vmcnt(0)" ::: "memory");
    __syncthreads();
    // phase 3: kts 6,7
    LOADA(B, 7)
    __builtin_amdgcn_sched_barrier(0);
    MFMAK(A, 6)
    __builtin_amdgcn_sched_barrier(0);
    MFMAK(B, 7)
#undef LOADA
#undef MFMAK
#undef STAGEB
    __syncthreads();                     // B LDS dead; safe to alias vbuf below

#define GETACC(N) ((N) == 0 ? acc0 : (N) == 1 ? acc1 : (N) == 2 ? acc2 : acc3)
    float* vbuf = (float*)smem;          // [64][129] f32 (33024B)
    const int proj = cb >> 2;            // 0:q 1:k 2:v 3:g
    if (proj == 0) {
        const float* ct = tab;
        const float* st = tab + LQ * HALF;
#pragma unroll
        for (int n = 0; n < 4; ++n) {
            const f16v acc = GETACC(n);
            int C = c0 + n * 32 + c31;
            int hh = (C & 511) >> 6;
            int hs = C & 63, i2 = hs >> 1;
            float sgn = (hs & 1) ? 1.f : -1.f;
#pragma unroll
            for (int r = 0; r < 16; ++r) {
                int lrow = wv * 32 + (r & 3) + 8 * (r >> 2) + 4 * hi;
                int pos = l0 + lrow;
                float val = acc[r];
                float part = __shfl_xor(val, 1);
                float res = val * ct[pos * HALF + i2] + sgn * part * st[pos * HALF + i2];
                qh[((size_t)hh * LQ + pos) * HS + hs] = f2bf(res);
            }
        }
    } else if (proj == 1) {
        const float* ct = tab + 2 * LQ * HALF;
        const float* st = tab + 3 * LQ * HALF;
#pragma unroll
        for (int p = 0; p < 2; ++p) {
            int hhp = ((c0 & 511) >> 6) + p;
            double lgd = -3.4657359027997265 + (double)hhp * (-2.772588722239781 / 7.0);
            float lgfp = (float)(log(1.0 - exp(lgd)) * 1.4426950408889634);
#pragma unroll
            for (int nn = 0; nn < 2; ++nn) {
                const int n = p * 2 + nn;
                const f16v acc = GETACC(n);
                int C = c0 + n * 32 + c31;
                int hs = C & 63, i2 = hs >> 1;
                float sgn = (hs & 1) ? 1.f : -1.f;
#pragma unroll
                for (int r = 0; r < 16; ++r) {
                    int lrow = wv * 32 + (r & 3) + 8 * (r >> 2) + 4 * hi;
                    int pos = l0 + lrow;
                    float val = acc[r];
                    float part = __shfl_xor(val, 1);
                    float res = val * ct[pos * HALF + i2] + sgn * part * st[pos * HALF + i2];
                    kh[((size_t)hhp * LQ + pos) * HS + hs] = f2bf(res);
                    float wf = exp2f(lgfp * (float)(64 - (pos & 63)));   // gamma^(64-m')
                    vbuf[(nn * 32 + c31) * 129 + lrow] = res * wf;
                }
            }
            __syncthreads();
            int cl = t >> 2, lseg = (t & 3) * 32;
            size_t o = ((size_t)hhp * HS + cl) * LQ + l0 + lseg;
#pragma unroll
            for (int ch4 = 0; ch4 < 4; ++ch4) {
                s8v pkh;
#pragma unroll
                for (int j = 0; j < 8; ++j) pkh[j] = (short)f2bf(vbuf[cl * 129 + lseg + ch4 * 8 + j]);
                *(s8v*)(ktw + o + ch4 * 8) = pkh;
            }
            __syncthreads();
        }
    } else if (proj == 2) {
#pragma unroll
        for (int p = 0; p < 2; ++p) {
            int hhp = ((c0 & 511) >> 6) + p;
#pragma unroll
            for (int nn = 0; nn < 2; ++nn) {
                const int n = p * 2 + nn;
                const f16v acc = GETACC(n);
                int cl_ = nn * 32 + c31;
#pragma unroll
                for (int r = 0; r < 16; ++r) {
                    int lrow = wv * 32 + (r & 3) + 8 * (r >> 2) + 4 * hi;
                    vbuf[cl_ * 129 + lrow] = acc[r];
                }
            }
            __syncthreads();
            int cl = t >> 2, lseg = (t & 3) * 32;
            size_t o = ((size_t)hhp * HS + cl) * LQ + l0 + lseg;
#pragma unroll
            for (int ch = 0; ch < 4; ++ch) {
                s8v pk;
#pragma unroll
                for (int j = 0; j < 8; ++j) pk[j] = (short)f2bf(vbuf[cl * 129 + lseg + ch * 8 + j]);
                *(s8v*)(vt + o + ch * 8) = pk;
            }
            __syncthreads();
        }
    } else {
#pragma unroll
        for (int n = 0; n < 4; ++n) {
            const f16v acc = GETACC(n);
            int C = (c0 & 511) + n * 32 + c31;
#pragma unroll
            for (int r = 0; r < 16; ++r) {
                int lrow = wv * 32 + (r & 3) + 8 * (r >> 2) + 4 * hi;
                float vv = acc[r];
                gate16[(size_t)(l0 + lrow) * DD + C] = f2bf(vv / (1.f + expf(-vv)));
            }
        }
    }
#undef GETACC
}

// ---------------- pass1: per-chunk state A^T[ch][d], 4 waves/chunk ----------------
__global__ __launch_bounds__(256) void k_ret1(
    const u16* __restrict__ vt, const u16* __restrict__ ktw,
    float* __restrict__ A) {
    const int t = threadIdx.x;
    const int c = blockIdx.x;
    const int h = blockIdx.y;
    const int wv = t >> 6, lane = t & 63, c31 = lane & 31, hi = lane >> 5;
    const int wch = wv >> 1, wd = wv & 1;

    s8v va[4];
    const u16* vp = vt + ((size_t)h * 64 + wch * 32 + c31) * LQ + c * 64 + hi * 8;
#pragma unroll
    for (int ks = 0; ks < 4; ++ks) va[ks] = *(const s8v*)(vp + ks * 16);

    f16v a;
#pragma unroll
    for (int i = 0; i < 16; ++i) a[i] = 0.f;

    const size_t kbase = ((size_t)h * 64 + wd * 32 + c31) * LQ + c * 64 + hi * 8;
#pragma unroll
    for (int ks = 0; ks < 4; ++ks) {
        s8v b_h = *(const s8v*)(ktw + kbase + ks * 16);
        a = __builtin_amdgcn_mfma_f32_32x32x16_bf16(va[ks], b_h, a, 0, 0, 0);
    }

    float* Ab = A + ((size_t)h * 64 + c) * 4096;
#pragma unroll
    for (int r = 0; r < 16; ++r) {
        int ch = wch * 32 + (r & 3) + 8 * (r >> 2) + 4 * hi;
        Ab[ch * 64 + wd * 32 + c31] = a[r];
    }
}

// ---------------- pass2: weighted prefix scan over chunks -> S^T bf16 ----------------
__global__ __launch_bounds__(256) void k_scan(
    const float* __restrict__ A, u16* __restrict__ sth) {
    const int bx = blockIdx.x;
    const int h = bx >> 4;
    const int e = (bx & 15) * 256 + threadIdx.x;
    double lg = -3.4657359027997265 + (double)h * (-2.772588722239781 / 7.0);
    double gamma = 1.0 - exp(lg);
    float g64 = (float)pow(gamma, 64.0);
    const float* Ab = A + (size_t)h * 64 * 4096 + e;
    u16* shb = sth + (size_t)h * 64 * 4096 + e;
    float av[64];
#pragma unroll
    for (int cc = 0; cc < 64; ++cc) av[cc] = Ab[(size_t)cc * 4096];
    float s = 0.f;
#pragma unroll
    for (int cc = 0; cc < 64; ++cc) {
        if (cc) shb[(size_t)cc * 4096] = f2bf(s);
        s = fmaf(g64, s, av[cc]);
    }
}

// ---------------- pass3: retention chunk + fused GroupNorm*gate -> frag-packed gg ----------------
// grid (64, 8), block 256 (4 waves). wave = (ws = row strip, wc = output col half).
__global__ __launch_bounds__(256) void k_ret3(
    const u16* __restrict__ qh, const u16* __restrict__ kh,
    const u16* __restrict__ vt, const u16* __restrict__ sth,
    const u16* __restrict__ gate16,
    const float* __restrict__ gw, const float* __restrict__ gb,
    u16* __restrict__ Gf) {
    __shared__ __align__(16) char sBuf[16640];   // KH 8K | VT 8K; later gT[64][65] f32
    __shared__ float stats[64][2][2];            // [row][wc][s,ss]
    const int t = threadIdx.x;
    const int c = blockIdx.x;
    const int h = blockIdx.y;
    const int wv = t >> 6, lane = t & 63, c31 = lane & 31, hi = lane >> 5;
    const int ws = wv >> 1, wc = wv & 1;
    const int l0q = c * 64;

    double lg = -3.4657359027997265 + (double)h * (-2.772588722239781 / 7.0);
    double gamma = 1.0 - exp(lg);
    float lgf = (float)(log(gamma) * 1.4426950408889634);
    float c1a[4], c8a[4];
#pragma unroll
    for (int m = 0; m < 4; ++m) { c1a[m] = exp2f(-lgf * (float)m); c8a[m] = exp2f(-lgf * (float)(8 * m)); }

    // Q fragments for this wave's row strip
    s8v qhf[4];
    {
        const u16* qph = qh + ((size_t)h * LQ + l0q + ws * 32 + c31) * HS + hi * 8;
#pragma unroll
        for (int ks = 0; ks < 4; ++ks) qhf[ks] = *(const s8v*)(qph + ks * 16);
    }

    // stage K + VT (pre-swizzled source, linear LDS dest), 4 x 16B per thread
    {
        const char* gKH = (const char*)kh + ((size_t)h * LQ + l0q) * 128;
        const char* gVT = (const char*)vt + ((size_t)h * 64) * 8192 + l0q * 2;
#pragma unroll
        for (int i_ = 0; i_ < 4; ++i_) {
            int boff = i_ * 4096 + t * 16;
            int seg = boff >> 13;
            int o_ = boff & 8191;
            int osrc = o_ ^ (((o_ >> 7) & 7) << 4);
            const char* src = (seg == 0) ? gKH + osrc
                            : gVT + (size_t)(osrc >> 7) * 8192 + (osrc & 127);
            gld16(sBuf + i_ * 4096 + (t >> 6) * 1024, src);
        }
    }

    // inter-chunk: qs = Q @ S^T for this wave's col half
    f16v qs;
#pragma unroll
    for (int i = 0; i < 16; ++i) qs[i] = 0.f;
    if (c > 0) {
        const u16* sbh = sth + ((size_t)h * 64 + c) * 4096;
#pragma unroll
        for (int ks = 0; ks < 4; ++ks) {
            int off = (wc * 32 + c31) * 64 + ks * 16 + hi * 8;
            s8v b_h = *(const s8v*)(sbh + off);
            qs = __builtin_amdgcn_mfma_f32_32x32x16_bf16(qhf[ks], b_h, qs, 0, 0, 0);
        }
    }

    asm volatile("s_waitcnt vmcnt(0)" ::: "memory");
    __syncthreads();

    // intra-chunk masked tile (QK^T duplicated across wc; PV split by wc)
    f16v acc;
#pragma unroll
    for (int i = 0; i < 16; ++i) acc[i] = 0.f;
    const char* bKH = sBuf;
    const char* bVT = sBuf + 8192;

#pragma unroll
    for (int jt = 0; jt < 2; ++jt) {
        if (ws == 0 && jt == 1) break;
        f16v sacc;
#pragma unroll
        for (int i = 0; i < 16; ++i) sacc[i] = 0.f;
#pragma unroll
        for (int ks = 0; ks < 4; ++ks) {
            int krow = jt * 32 + c31;
            int ph = krow * 128 + ((ks * 32 + hi * 16) ^ ((krow & 7) << 4));
            s8v ah = *(const s8v*)(bKH + ph);
            sacc = __builtin_amdgcn_mfma_f32_32x32x16_bf16(ah, qhf[ks], sacc, 0, 0, 0);
        }
        const int D0 = (ws * 32 + c31) - jt * 32;
        float base = exp2f(lgf * (float)(D0 - 4 * hi));
        u32 w[8];
#pragma unroll
        for (int g = 0; g < 4; ++g) {
            float wg = base * c8a[g];
            float v0 = sacc[4 * g + 0] * (wg * c1a[0]);
            float v1 = sacc[4 * g + 1] * (wg * c1a[1]);
            float v2 = sacc[4 * g + 2] * (wg * c1a[2]);
            float v3 = sacc[4 * g + 3] * (wg * c1a[3]);
            int jr = 8 * g + 4 * hi;
            if (D0 - (jr + 0) < 0) v0 = 0.f;
            if (D0 - (jr + 1) < 0) v1 = 0.f;
            if (D0 - (jr + 2) < 0) v2 = 0.f;
            if (D0 - (jr + 3) < 0) v3 = 0.f;
            w[2 * g]     = (u32)f2bf(v0) | ((u32)f2bf(v1) << 16);
            w[2 * g + 1] = (u32)f2bf(v2) | ((u32)f2bf(v3) << 16);
        }
        u32 e0 = __shfl_xor(hi ? w[0] : w[2], 32);
        u32 e1 = __shfl_xor(hi ? w[1] : w[3], 32);
        u32 e2 = __shfl_xor(hi ? w[4] : w[6], 32);
        u32 e3 = __shfl_xor(hi ? w[5] : w[7], 32);
        u32x4 a0v = { hi ? e0 : w[0], hi ? e1 : w[1], hi ? w[2] : e0, hi ? w[3] : e1 };
        u32x4 a1v = { hi ? e2 : w[4], hi ? e3 : w[5], hi ? w[6] : e2, hi ? w[7] : e3 };
        s8v af0 = __builtin_bit_cast(s8v, a0v);
        s8v af1 = __builtin_bit_cast(s8v, a1v);
#pragma unroll
        for (int ksl = 0; ksl < 2; ++ksl) {
            s8v af = ksl ? af1 : af0;
            int cb = (jt * 2 + ksl) * 32 + hi * 16;
            int rv = wc * 32 + c31;
            s8v vb = *(const s8v*)(bVT + rv * 128 + (cb ^ ((rv & 7) << 4)));
            acc = __builtin_amdgcn_mfma_f32_32x32x16_bf16(af, vb, acc, 0, 0, 0);
        }
    }

    // epilogue: combine inter+intra; cross-wc GroupNorm stats via LDS; *gate; frag-pack gg
    float vv[16];
#pragma unroll
    for (int r = 0; r < 16; ++r) {
        int row = (r & 3) + 8 * (r >> 2) + 4 * hi;
        int nloc = ws * 32 + row;
        float sc = exp2f(lgf * (float)nloc);
        vv[r] = acc[r] + sc * qs[r];
    }
#pragma unroll
    for (int r = 0; r < 16; ++r) {
        float s = vv[r], ss = vv[r] * vv[r];
#pragma unroll
        for (int off = 1; off < 32; off <<= 1) {
            s  += __shfl_xor(s, off);
            ss += __shfl_xor(ss, off);
        }
        if (c31 == 0) {
            int nloc = ws * 32 + (r & 3) + 8 * (r >> 2) + 4 * hi;
            stats[nloc][wc][0] = s;
            stats[nloc][wc][1] = ss;
        }
    }
    __syncthreads();   // stats ready; all sBuf (K/V) reads also done -> safe to alias gT

    float* gT = (float*)sBuf;           // [64][65] f32
    const float gwv = gw[h * HS + wc * 32 + c31];
    const float gbv = gb[h * HS + wc * 32 + c31];
#pragma unroll
    for (int r = 0; r < 16; ++r) {
        int nloc = ws * 32 + (r & 3) + 8 * (r >> 2) + 4 * hi;
        float s  = stats[nloc][0][0] + stats[nloc][1][0];
        float ss = stats[nloc][0][1] + stats[nloc][1][1];
        float mean = s * (1.f / 64.f);
        float var = ss * (1.f / 64.f) - mean * mean;
        float inv = rsqrtf(var + 1e-5f);
        size_t o = (size_t)(l0q + nloc) * DD + h * HS + wc * 32 + c31;
        float g = ((vv[r] - mean) * inv * gwv + gbv) * bf2f(gate16[o]);
        gT[nloc * 65 + wc * 32 + c31] = g;
    }
    __syncthreads();
#pragma unroll
    for (int i = 0; i < 2; ++i) {
        int u = t + i * 256;            // 0..511
        int rbl = u >> 8;
        int ks = (u >> 6) & 3;
        int ln = u & 63;
        int row = rbl * 32 + (ln & 31);
        int ch = ks * 16 + (ln >> 5) * 8;
        s8v pk;
#pragma unroll
        for (int j = 0; j < 8; ++j) pk[j] = (short)f2bf(gT[row * 65 + ch + j]);
        size_t off = ((((size_t)(c * 2 + rbl) * 8 + h) * 4 + ks) * 64 + ln) * 8;
        *(s8v*)(Gf + off) = pk;
    }
}

// ---------------- out = gg @ W_O (A frag-direct pinned, B LDS-shared 2 phases) ----------------
__global__ __launch_bounds__(256) void k_out(
    const u16* __restrict__ Gf, const u16* __restrict__ Wf,
    float* __restrict__ out) {
    __shared__ __align__(16) char smem[32768];
    const int t = threadIdx.x;
    const int l0 = blockIdx.x * 128;
    const int c0 = blockIdx.y * 64;
    const int wv = t >> 6;
    const int lane = t & 63;
    const int c31 = lane & 31;
    const int hi = lane >> 5;

    const int rb = blockIdx.x * 4 + wv;
    const u16* pA  = Gf + (size_t)rb * 16384 + lane * 8;
    const char* gB = (const char*)(Wf + (size_t)(64 + blockIdx.y * 2) * 16384);

    f16v acc0, acc1;
#pragma unroll
    for (int i = 0; i < 16; ++i) { acc0[i] = 0.f; acc1[i] = 0.f; }

#define STAGEB(PH)                                                             \
    { _Pragma("unroll") for (int j = 0; j < 8; ++j) {                          \
        int seg = j >> 2, q4 = j & 3;                                          \
        gld16(smem + seg * 16384 + q4 * 4096 + wv * 1024,                      \
              gB + seg * 32768 + (PH) * 16384 + q4 * 4096 + t * 16); } }
    s8v aA[4], aB[4];
#define LOADO(S, KT)                                                      \
    { _Pragma("unroll") for (int ks = 0; ks < 4; ++ks) {                  \
        a##S[ks] = *(const s8v*)(pA + (KT) * 2048 + ks * 512); } }
#define MFMAO(S, KT)                                                                        \
    { const char* bbq = smem + ((KT) & 3) * 4096;                                           \
      _Pragma("unroll") for (int ks = 0; ks < 4; ++ks) {                                    \
        s8v b0 = *(const s8v*)(bbq + ks * 1024 + lane * 16);                                \
        s8v b1 = *(const s8v*)(bbq + 16384 + ks * 1024 + lane * 16);                        \
        acc0 = __builtin_amdgcn_mfma_f32_32x32x16_bf16(a##S[ks], b0, acc0, 0, 0, 0);        \
        acc1 = __builtin_amdgcn_mfma_f32_32x32x16_bf16(a##S[ks], b1, acc1, 0, 0, 0); } }
    STAGEB(0)
    LOADO(A, 0)
    asm volatile("s_waitcnt vmcnt(0)" ::: "memory");
    __syncthreads();
    LOADO(B, 1)
    __builtin_amdgcn_sched_barrier(0);
    MFMAO(A, 0)
    LOADO(A, 2)
    __builtin_amdgcn_sched_barrier(0);
    MFMAO(B, 1)
    LOADO(B, 3)
    __builtin_amdgcn_sched_barrier(0);
    MFMAO(A, 2)
    LOADO(A, 4)
    __builtin_amdgcn_sched_barrier(0);
    MFMAO(B, 3)
    __syncthreads();
    STAGEB(1)
    asm volatile("s_waitcnt vmcnt(0)" ::: "memory");
    __syncthreads();
    LOADO(B, 5)
    __builtin_amdgcn_sched_barrier(0);
    MFMAO(A, 4)
    LOADO(A, 6)
    __builtin_amdgcn_sched_barrier(0);
    MFMAO(B, 5)
    LOADO(B, 7)
    __builtin_amdgcn_sched_barrier(0);
    MFMAO(A, 6)
    __builtin_amdgcn_sched_barrier(0);
    MFMAO(B, 7)
#undef LOADO
#undef MFMAO
#undef STAGEB

#pragma unroll
    for (int n = 0; n < 2; ++n) {
        const f16v acc = n ? acc1 : acc0;
        int C = c0 + n * 32 + c31;
#pragma unroll
        for (int r = 0; r < 16; ++r) {
            int lrow = wv * 32 + (r & 3) + 8 * (r >> 2) + 4 * hi;
            out[(size_t)(l0 + lrow) * DD + C] = acc[r];
        }
    }
}

extern "C" void kernel_launch(void* const* d_in, const int* in_sizes, int n_in,
                              void* d_out, int out_size, void* d_ws, size_t ws_size,
                              hipStream_t stream) {
    const float* X   = (const float*)d_in[0];
    const float* W_Q = (const float*)d_in[1];
    const float* W_K = (const float*)d_in[2];
    const float* W_V = (const float*)d_in[3];
    const float* W_G = (const float*)d_in[4];
    const float* W_O = (const float*)d_in[5];
    const float* gnw = (const float*)d_in[6];
    const float* gnb = (const float*)d_in[7];

    float* ws   = (float*)d_ws;
    u16* qhp  = (u16*)(ws + WS_QH);
    u16* khp  = (u16*)(ws + WS_KH);
    u16* vtp  = (u16*)(ws + WS_VT);
    u16* xfp  = (u16*)(ws + WS_XFH);
    u16* wf   = (u16*)(ws + WS_WF);
    u16* gate16 = (u16*)(ws + WS_GATE);
    float* tab  = ws + WS_TAB;
    u16* ktwp = (u16*)(ws + WS_KTWH);
    float* Abuf = ws + WS_XFH;         // A_state over dead Xf (2M floats, spans XFH+XFL)
    u16* sthp = (u16*)(ws + WS_KTWH);  // St over dead ktw
    u16* Gfp  = (u16*)(ws + WS_XFH);   // frag-packed gg over dead A_state
    float* out  = (float*)d_out;

    k_pre<<<2816, 256, 0, stream>>>(X, W_Q, W_K, W_V, W_G, W_O, tab, xfp, wf);
    k_fused<<<512, 256, 0, stream>>>(xfp, wf, tab, qhp, khp, vtp, gate16, ktwp);
    k_ret1<<<dim3(64, 8), 256, 0, stream>>>(vtp, ktwp, Abuf);
    k_scan<<<128, 256, 0, stream>>>(Abuf, sthp);
    k_ret3<<<dim3(64, 8), 256, 0, stream>>>(qhp, khp, vtp, sthp, gate16, gnw, gnb, Gfp);
    k_out<<<dim3(32, 8), 256, 0, stream>>>(Gfp, wf, out);
}

// Round 12
// 69.621 us; speedup vs baseline: 1.0823x; 1.0823x over previous
//
#include <hip/hip_runtime.h>
#include <math.h>

#define LQ 4096
#define DD 512
#define NH 8
#define HS 64
#define HALF 32

typedef unsigned short u16;
typedef unsigned int u32;
typedef __attribute__((ext_vector_type(8)))  short s8v;   // 8 x bf16 (MFMA A/B frag)
typedef __attribute__((ext_vector_type(4)))  float f4v;
typedef __attribute__((ext_vector_type(4)))  u32  u32x4;
typedef __attribute__((ext_vector_type(16))) float f16v;  // 32x32 MFMA C/D

// workspace offsets (in floats)
#define WS_QH   0u
#define WS_KH   2097152u
#define WS_KL   3145728u    // unused
#define WS_VT   4194304u
#define WS_XFH  5242880u    // frag-packed X (bf16); later A_state spans XFH+XFL; later Gf
#define WS_XFL  6291456u
#define WS_WF   7340032u    // frag-packed W bf16
#define WS_GATE 8650752u    // gate bf16
#define WS_TAB  10747904u
#define WS_KTWH 11272192u   // ktw; later St

__device__ inline u16 f2bf(float x) {
    unsigned int u = __float_as_uint(x);
    return (u16)((u + 0x7fffu + ((u >> 16) & 1u)) >> 16);
}
__device__ inline float bf2f(u16 h) { return __uint_as_float(((unsigned int)h) << 16); }

__device__ __forceinline__ void gld16(void* lds, const void* g) {
    __builtin_amdgcn_global_load_lds(
        (const __attribute__((address_space(1))) void*)g,
        (__attribute__((address_space(3))) void*)lds, 16, 0, 0);
}

// ---------------- merged prep: xPos tables | X->frag bf16 | W->frag bf16 ----------------
__global__ __launch_bounds__(256) void k_pre(
    const float* __restrict__ X,
    const float* __restrict__ Wq, const float* __restrict__ Wk, const float* __restrict__ Wv,
    const float* __restrict__ Wg, const float* __restrict__ Wo,
    float* __restrict__ tab, u16* __restrict__ Xf, u16* __restrict__ Wf) {
    __shared__ float tile[32][33];
    const int b = blockIdx.x;
    const int t = threadIdx.x;
    if (b < 512) {
        int idx = b * 256 + t;
        if (idx >= LQ * HALF) return;
        int l = idx >> 5;
        int i = idx & 31;
        double log2sv = log2((2.0 * i + 25.6) / 89.6);
        double e = (double)l * log2sv * (1.0 / 512.0);
        float sc  = exp2f((float)e);
        float sci = exp2f((float)(-e));
        double invf = exp2((double)i * (-13.287712379549449 / 32.0));
        double th = (double)l * invf;
        double r = th - 6.283185307179586 * floor(th * 0.15915494309189535);
        float c = cosf((float)r), sn = sinf((float)r);
        tab[idx]                 = c * sc;
        tab[LQ*HALF + idx]       = sn * sc;
        tab[2*LQ*HALF + idx]     = c * sci;
        tab[3*LQ*HALF + idx]     = sn * sci;
    } else if (b < 1536) {
        // X -> fragment-packed bf16: Xf[rb:128][kt:8][ks:4][lane:64][8]
        int g = (b - 512) * 256 + t;
        int l = g >> 6;
        int d = (g & 63) * 8;
        const float* xp = X + (size_t)l * DD + d;
        f4v x0 = *(const f4v*)xp;
        f4v x1 = *(const f4v*)(xp + 4);
        s8v ph;
#pragma unroll
        for (int j = 0; j < 4; ++j) {
            ph[j]   = (short)f2bf(x0[j]);
            ph[j+4] = (short)f2bf(x1[j]);
        }
        int rb = l >> 5, kt = d >> 6, ks = (d >> 4) & 3, kh2 = (d >> 3) & 1;
        int lane = kh2 * 32 + (l & 31);
        size_t off = (((size_t)(rb * 8 + kt) * 4 + ks) * 64 + lane) * 8;
        *(s8v*)(Xf + off) = ph;
    } else {
        // weights -> fragment-packed bf16: Wf[nb:80][kt:8][ks:4][lane:64][8]
        int bb = b - 1536;
        int d0 = (bb & 15) * 32, C0 = (bb >> 4) * 32;
        int proj = C0 >> 9;
        int tc = t & 31, tr = t >> 5;
#pragma unroll
        for (int rr = 0; rr < 4; ++rr) {
            int dl = tr + rr * 8;
            int d = d0 + dl;
            int C = C0 + tc;
            float val;
            if (proj < 3) {
                const float* W = (proj == 0) ? Wq : ((proj == 1) ? Wk : Wv);
                int h = (C & 511) >> 6, hs = C & 63;
                val = W[(size_t)h * (DD * HS) + (size_t)d * HS + hs];
            } else if (proj == 3) {
                val = Wg[(size_t)d * DD + (C & 511)];
            } else {
                val = Wo[(size_t)d * DD + (C - 2048)];
            }
            tile[dl][tc] = val;
        }
        __syncthreads();
        if (t < 128) {
            int cl = t & 31, dgq = t >> 5;
            int dl = dgq * 8;
            s8v pk;
#pragma unroll
            for (int j = 0; j < 8; ++j) pk[j] = (short)f2bf(tile[dl + j][cl]);
            int C = C0 + cl;
            int da = d0 + dl;
            int nb = C >> 5, kt = da >> 6, ks = (da >> 4) & 3, kh2 = (da >> 3) & 1;
            int lane = kh2 * 32 + (C & 31);
            size_t off = (((size_t)(nb * 8 + kt) * 4 + ks) * 64 + lane) * 8;
            *(s8v*)(Wf + off) = pk;
        }
    }
}

// ---------------- fused MFMA GEMM: 128x64 blocks, full-B staged once, single barrier ----------------
// grid 1024 (XCD-chunked swizzle), block 256 (4 waves, each 32l x 64c).
__global__ __launch_bounds__(256) void k_fused(
    const u16* __restrict__ Xf, const u16* __restrict__ Wf,
    const float* __restrict__ tab,
    u16* __restrict__ qh, u16* __restrict__ kh,
    u16* __restrict__ vt, u16* __restrict__ gate16,
    u16* __restrict__ ktw) {
    __shared__ __align__(16) char smem[65536];   // B [nb:2][kt:8][4KB]; vbuf alias after loop
    const int t = threadIdx.x;
    const int b = blockIdx.x;
    const int mb = (b & 7) * 4 + (b >> 8);   // 0..31, XCD-chunked
    const int cb = (b >> 3) & 31;            // 0..31
    const int l0 = mb * 128;
    const int c0 = cb * 64;
    const int wv = t >> 6;
    const int lane = t & 63;
    const int c31 = lane & 31;
    const int hi = lane >> 5;

    const int rb = mb * 4 + wv;
    const u16* pA = Xf + (size_t)rb * 16384 + lane * 8;
    const char* gB = (const char*)(Wf + (size_t)(cb * 2) * 16384);

    f16v acc0, acc1;
#pragma unroll
    for (int i = 0; i < 16; ++i) { acc0[i] = 0.f; acc1[i] = 0.f; }

    // stage ALL of B (64KB) once; layout identical to source (linear frag order)
#pragma unroll
    for (int j = 0; j < 16; ++j)
        gld16(smem + j * 4096 + wv * 1024, gB + j * 4096 + t * 16);
    __builtin_amdgcn_sched_barrier(0);

    s8v aA[4], aB[4], aC[4];
#define LOADA(S, KT)                                                      \
    { _Pragma("unroll") for (int ks = 0; ks < 4; ++ks) {                  \
        a##S[ks] = *(const s8v*)(pA + (KT) * 2048 + ks * 512); } }
#define MFMAK(S, KT)                                                                        \
    { const char* bbq = smem + (KT) * 4096;                                                 \
      _Pragma("unroll") for (int ks = 0; ks < 4; ++ks) {                                    \
        s8v b0 = *(const s8v*)(bbq + ks * 1024 + lane * 16);                                \
        s8v b1 = *(const s8v*)(bbq + 32768 + ks * 1024 + lane * 16);                        \
        acc0 = __builtin_amdgcn_mfma_f32_32x32x16_bf16(a##S[ks], b0, acc0, 0, 0, 0);        \
        acc1 = __builtin_amdgcn_mfma_f32_32x32x16_bf16(a##S[ks], b1, acc1, 0, 0, 0); } }

    LOADA(A, 0)
    LOADA(B, 1)
    __builtin_amdgcn_sched_barrier(0);
    asm volatile("s_waitcnt vmcnt(8)" ::: "memory");   // all 16 stages done; 8 A-loads in flight
    __syncthreads();
    LOADA(C, 2)
    __builtin_amdgcn_sched_barrier(0);
    MFMAK(A, 0)
    LOADA(A, 3)
    __builtin_amdgcn_sched_barrier(0);
    MFMAK(B, 1)
    LOADA(B, 4)
    __builtin_amdgcn_sched_barrier(0);
    MFMAK(C, 2)
    LOADA(C, 5)
    __builtin_amdgcn_sched_barrier(0);
    MFMAK(A, 3)
    LOADA(A, 6)
    __builtin_amdgcn_sched_barrier(0);
    MFMAK(B, 4)
    LOADA(B, 7)
    __builtin_amdgcn_sched_barrier(0);
    MFMAK(C, 5)
    __builtin_amdgcn_sched_barrier(0);
    MFMAK(A, 6)
    __builtin_amdgcn_sched_barrier(0);
    MFMAK(B, 7)
#undef LOADA
#undef MFMAK
    __syncthreads();                     // B LDS dead; safe to alias vbuf below

    float* vbuf = (float*)smem;          // [64][129] f32
    const int proj = c0 >> 9;
    if (proj < 2) {
        const float* ct = tab + (proj ? 2 * LQ * HALF : 0);
        const float* st = tab + (proj ? 3 * LQ * HALF : LQ * HALF);
        u16* oh = proj ? kh : qh;
        const int hh = (c0 & 511) >> 6;
        float lgf = 0.f;
        if (proj == 1) {
            double lg = -3.4657359027997265 + (double)hh * (-2.772588722239781 / 7.0);
            lgf = (float)(log(1.0 - exp(lg)) * 1.4426950408889634);
        }
#pragma unroll
        for (int n = 0; n < 2; ++n) {
            const f16v acc = n ? acc1 : acc0;
            int C = c0 + n * 32 + c31;
            int hs = C & 63, i2 = hs >> 1;
            float sgn = (hs & 1) ? 1.f : -1.f;
#pragma unroll
            for (int r = 0; r < 16; ++r) {
                int lrow = wv * 32 + (r & 3) + 8 * (r >> 2) + 4 * hi;
                int pos = l0 + lrow;
                float val = acc[r];
                float part = __shfl_xor(val, 1);
                float res = val * ct[pos * HALF + i2] + sgn * part * st[pos * HALF + i2];
                size_t o = ((size_t)hh * LQ + pos) * HS + hs;
                oh[o] = f2bf(res);
                if (proj == 1) {
                    float wf = exp2f(lgf * (float)(64 - (pos & 63)));   // gamma^(64-m')
                    vbuf[(n * 32 + c31) * 129 + lrow] = res * wf;
                }
            }
        }
        if (proj == 1) {
            __syncthreads();
            int cl = t >> 2, lseg = (t & 3) * 32;
            size_t o = ((size_t)hh * HS + cl) * LQ + l0 + lseg;
#pragma unroll
            for (int ch4 = 0; ch4 < 4; ++ch4) {
                s8v pkh;
#pragma unroll
                for (int j = 0; j < 8; ++j) pkh[j] = (short)f2bf(vbuf[cl * 129 + lseg + ch4 * 8 + j]);
                *(s8v*)(ktw + o + ch4 * 8) = pkh;
            }
        }
    } else if (proj == 2) {
#pragma unroll
        for (int n = 0; n < 2; ++n) {
            const f16v acc = n ? acc1 : acc0;
            int cl = n * 32 + c31;
#pragma unroll
            for (int r = 0; r < 16; ++r) {
                int lrow = wv * 32 + (r & 3) + 8 * (r >> 2) + 4 * hi;
                vbuf[cl * 129 + lrow] = acc[r];
            }
        }
        __syncthreads();
        int h = (c0 & 511) >> 6;
        int cl = t >> 2, lseg = (t & 3) * 32;
        size_t o = ((size_t)h * HS + cl) * LQ + l0 + lseg;
#pragma unroll
        for (int ch = 0; ch < 4; ++ch) {
            s8v pk;
#pragma unroll
            for (int j = 0; j < 8; ++j) pk[j] = (short)f2bf(vbuf[cl * 129 + lseg + ch * 8 + j]);
            *(s8v*)(vt + o + ch * 8) = pk;
        }
    } else {
#pragma unroll
        for (int n = 0; n < 2; ++n) {
            const f16v acc = n ? acc1 : acc0;
            int C = (c0 & 511) + n * 32 + c31;
#pragma unroll
            for (int r = 0; r < 16; ++r) {
                int lrow = wv * 32 + (r & 3) + 8 * (r >> 2) + 4 * hi;
                float vv = acc[r];
                gate16[(size_t)(l0 + lrow) * DD + C] = f2bf(vv / (1.f + expf(-vv)));
            }
        }
    }
}

// ---------------- pass1: per-chunk state A^T[ch][d], 4 waves/chunk ----------------
__global__ __launch_bounds__(256) void k_ret1(
    const u16* __restrict__ vt, const u16* __restrict__ ktw,
    float* __restrict__ A) {
    const int t = threadIdx.x;
    const int c = blockIdx.x;
    const int h = blockIdx.y;
    const int wv = t >> 6, lane = t & 63, c31 = lane & 31, hi = lane >> 5;
    const int wch = wv >> 1, wd = wv & 1;

    s8v va[4];
    const u16* vp = vt + ((size_t)h * 64 + wch * 32 + c31) * LQ + c * 64 + hi * 8;
#pragma unroll
    for (int ks = 0; ks < 4; ++ks) va[ks] = *(const s8v*)(vp + ks * 16);

    f16v a;
#pragma unroll
    for (int i = 0; i < 16; ++i) a[i] = 0.f;

    const size_t kbase = ((size_t)h * 64 + wd * 32 + c31) * LQ + c * 64 + hi * 8;
#pragma unroll
    for (int ks = 0; ks < 4; ++ks) {
        s8v b_h = *(const s8v*)(ktw + kbase + ks * 16);
        a = __builtin_amdgcn_mfma_f32_32x32x16_bf16(va[ks], b_h, a, 0, 0, 0);
    }

    float* Ab = A + ((size_t)h * 64 + c) * 4096;
#pragma unroll
    for (int r = 0; r < 16; ++r) {
        int ch = wch * 32 + (r & 3) + 8 * (r >> 2) + 4 * hi;
        Ab[ch * 64 + wd * 32 + c31] = a[r];
    }
}

// ---------------- pass2: weighted prefix scan over chunks -> S^T bf16 ----------------
__global__ __launch_bounds__(256) void k_scan(
    const float* __restrict__ A, u16* __restrict__ sth) {
    const int bx = blockIdx.x;
    const int h = bx >> 4;
    const int e = (bx & 15) * 256 + threadIdx.x;
    double lg = -3.4657359027997265 + (double)h * (-2.772588722239781 / 7.0);
    double gamma = 1.0 - exp(lg);
    float g64 = (float)pow(gamma, 64.0);
    const float* Ab = A + (size_t)h * 64 * 4096 + e;
    u16* shb = sth + (size_t)h * 64 * 4096 + e;
    float av[64];
#pragma unroll
    for (int cc = 0; cc < 64; ++cc) av[cc] = Ab[(size_t)cc * 4096];
    float s = 0.f;
#pragma unroll
    for (int cc = 0; cc < 64; ++cc) {
        if (cc) shb[(size_t)cc * 4096] = f2bf(s);
        s = fmaf(g64, s, av[cc]);
    }
}

// ---------------- pass3: retention chunk + fused GroupNorm*gate -> frag-packed gg ----------------
// grid (64, 8), block 256 (4 waves). wave = (ws = row strip, wc = output col half).
__global__ __launch_bounds__(256) void k_ret3(
    const u16* __restrict__ qh, const u16* __restrict__ kh,
    const u16* __restrict__ vt, const u16* __restrict__ sth,
    const u16* __restrict__ gate16,
    const float* __restrict__ gw, const float* __restrict__ gb,
    u16* __restrict__ Gf) {
    __shared__ __align__(16) char sBuf[16640];   // KH 8K | VT 8K; later gT[64][65] f32
    __shared__ float stats[64][2][2];            // [row][wc][s,ss]
    const int t = threadIdx.x;
    const int c = blockIdx.x;
    const int h = blockIdx.y;
    const int wv = t >> 6, lane = t & 63, c31 = lane & 31, hi = lane >> 5;
    const int ws = wv >> 1, wc = wv & 1;
    const int l0q = c * 64;

    double lg = -3.4657359027997265 + (double)h * (-2.772588722239781 / 7.0);
    double gamma = 1.0 - exp(lg);
    float lgf = (float)(log(gamma) * 1.4426950408889634);
    float c1a[4], c8a[4];
#pragma unroll
    for (int m = 0; m < 4; ++m) { c1a[m] = exp2f(-lgf * (float)m); c8a[m] = exp2f(-lgf * (float)(8 * m)); }

    // Q fragments for this wave's row strip
    s8v qhf[4];
    {
        const u16* qph = qh + ((size_t)h * LQ + l0q + ws * 32 + c31) * HS + hi * 8;
#pragma unroll
        for (int ks = 0; ks < 4; ++ks) qhf[ks] = *(const s8v*)(qph + ks * 16);
    }

    // stage K + VT (pre-swizzled source, linear LDS dest), 4 x 16B per thread
    {
        const char* gKH = (const char*)kh + ((size_t)h * LQ + l0q) * 128;
        const char* gVT = (const char*)vt + ((size_t)h * 64) * 8192 + l0q * 2;
#pragma unroll
        for (int i_ = 0; i_ < 4; ++i_) {
            int boff = i_ * 4096 + t * 16;
            int seg = boff >> 13;
            int o_ = boff & 8191;
            int osrc = o_ ^ (((o_ >> 7) & 7) << 4);
            const char* src = (seg == 0) ? gKH + osrc
                            : gVT + (size_t)(osrc >> 7) * 8192 + (osrc & 127);
            gld16(sBuf + i_ * 4096 + (t >> 6) * 1024, src);
        }
    }

    // inter-chunk: qs = Q @ S^T for this wave's col half
    f16v qs;
#pragma unroll
    for (int i = 0; i < 16; ++i) qs[i] = 0.f;
    if (c > 0) {
        const u16* sbh = sth + ((size_t)h * 64 + c) * 4096;
#pragma unroll
        for (int ks = 0; ks < 4; ++ks) {
            int off = (wc * 32 + c31) * 64 + ks * 16 + hi * 8;
            s8v b_h = *(const s8v*)(sbh + off);
            qs = __builtin_amdgcn_mfma_f32_32x32x16_bf16(qhf[ks], b_h, qs, 0, 0, 0);
        }
    }

    asm volatile("s_waitcnt vmcnt(0)" ::: "memory");
    __syncthreads();

    // intra-chunk masked tile (QK^T duplicated across wc; PV split by wc)
    f16v acc;
#pragma unroll
    for (int i = 0; i < 16; ++i) acc[i] = 0.f;
    const char* bKH = sBuf;
    const char* bVT = sBuf + 8192;

#pragma unroll
    for (int jt = 0; jt < 2; ++jt) {
        if (ws == 0 && jt == 1) break;
        f16v sacc;
#pragma unroll
        for (int i = 0; i < 16; ++i) sacc[i] = 0.f;
#pragma unroll
        for (int ks = 0; ks < 4; ++ks) {
            int krow = jt * 32 + c31;
            int ph = krow * 128 + ((ks * 32 + hi * 16) ^ ((krow & 7) << 4));
            s8v ah = *(const s8v*)(bKH + ph);
            sacc = __builtin_amdgcn_mfma_f32_32x32x16_bf16(ah, qhf[ks], sacc, 0, 0, 0);
        }
        const int D0 = (ws * 32 + c31) - jt * 32;
        float base = exp2f(lgf * (float)(D0 - 4 * hi));
        u32 w[8];
#pragma unroll
        for (int g = 0; g < 4; ++g) {
            float wg = base * c8a[g];
            float v0 = sacc[4 * g + 0] * (wg * c1a[0]);
            float v1 = sacc[4 * g + 1] * (wg * c1a[1]);
            float v2 = sacc[4 * g + 2] * (wg * c1a[2]);
            float v3 = sacc[4 * g + 3] * (wg * c1a[3]);
            int jr = 8 * g + 4 * hi;
            if (D0 - (jr + 0) < 0) v0 = 0.f;
            if (D0 - (jr + 1) < 0) v1 = 0.f;
            if (D0 - (jr + 2) < 0) v2 = 0.f;
            if (D0 - (jr + 3) < 0) v3 = 0.f;
            w[2 * g]     = (u32)f2bf(v0) | ((u32)f2bf(v1) << 16);
            w[2 * g + 1] = (u32)f2bf(v2) | ((u32)f2bf(v3) << 16);
        }
        u32 e0 = __shfl_xor(hi ? w[0] : w[2], 32);
        u32 e1 = __shfl_xor(hi ? w[1] : w[3], 32);
        u32 e2 = __shfl_xor(hi ? w[4] : w[6], 32);
        u32 e3 = __shfl_xor(hi ? w[5] : w[7], 32);
        u32x4 a0v = { hi ? e0 : w[0], hi ? e1 : w[1], hi ? w[2] : e0, hi ? w[3] : e1 };
        u32x4 a1v = { hi ? e2 : w[4], hi ? e3 : w[5], hi ? w[6] : e2, hi ? w[7] : e3 };
        s8v af0 = __builtin_bit_cast(s8v, a0v);
        s8v af1 = __builtin_bit_cast(s8v, a1v);
#pragma unroll
        for (int ksl = 0; ksl < 2; ++ksl) {
            s8v af = ksl ? af1 : af0;
            int cb = (jt * 2 + ksl) * 32 + hi * 16;
            int rv = wc * 32 + c31;
            s8v vb = *(const s8v*)(bVT + rv * 128 + (cb ^ ((rv & 7) << 4)));
            acc = __builtin_amdgcn_mfma_f32_32x32x16_bf16(af, vb, acc, 0, 0, 0);
        }
    }

    // epilogue: combine inter+intra; cross-wc GroupNorm stats via LDS; *gate; frag-pack gg
    float vv[16];
#pragma unroll
    for (int r = 0; r < 16; ++r) {
        int row = (r & 3) + 8 * (r >> 2) + 4 * hi;
        int nloc = ws * 32 + row;
        float sc = exp2f(lgf * (float)nloc);
        vv[r] = acc[r] + sc * qs[r];
    }
#pragma unroll
    for (int r = 0; r < 16; ++r) {
        float s = vv[r], ss = vv[r] * vv[r];
#pragma unroll
        for (int off = 1; off < 32; off <<= 1) {
            s  += __shfl_xor(s, off);
            ss += __shfl_xor(ss, off);
        }
        if (c31 == 0) {
            int nloc = ws * 32 + (r & 3) + 8 * (r >> 2) + 4 * hi;
            stats[nloc][wc][0] = s;
            stats[nloc][wc][1] = ss;
        }
    }
    __syncthreads();   // stats ready; all sBuf (K/V) reads also done -> safe to alias gT

    float* gT = (float*)sBuf;           // [64][65] f32
    const float gwv = gw[h * HS + wc * 32 + c31];
    const float gbv = gb[h * HS + wc * 32 + c31];
#pragma unroll
    for (int r = 0; r < 16; ++r) {
        int nloc = ws * 32 + (r & 3) + 8 * (r >> 2) + 4 * hi;
        float s  = stats[nloc][0][0] + stats[nloc][1][0];
        float ss = stats[nloc][0][1] + stats[nloc][1][1];
        float mean = s * (1.f / 64.f);
        float var = ss * (1.f / 64.f) - mean * mean;
        float inv = rsqrtf(var + 1e-5f);
        size_t o = (size_t)(l0q + nloc) * DD + h * HS + wc * 32 + c31;
        float g = ((vv[r] - mean) * inv * gwv + gbv) * bf2f(gate16[o]);
        gT[nloc * 65 + wc * 32 + c31] = g;
    }
    __syncthreads();
#pragma unroll
    for (int i = 0; i < 2; ++i) {
        int u = t + i * 256;            // 0..511
        int rbl = u >> 8;
        int ks = (u >> 6) & 3;
        int ln = u & 63;
        int row = rbl * 32 + (ln & 31);
        int ch = ks * 16 + (ln >> 5) * 8;
        s8v pk;
#pragma unroll
        for (int j = 0; j < 8; ++j) pk[j] = (short)f2bf(gT[row * 65 + ch + j]);
        size_t off = ((((size_t)(c * 2 + rbl) * 8 + h) * 4 + ks) * 64 + ln) * 8;
        *(s8v*)(Gf + off) = pk;
    }
}

// ---------------- out = gg @ W_O (full-B staged once, single barrier) ----------------
__global__ __launch_bounds__(256) void k_out(
    const u16* __restrict__ Gf, const u16* __restrict__ Wf,
    float* __restrict__ out) {
    __shared__ __align__(16) char smem[65536];
    const int t = threadIdx.x;
    const int l0 = blockIdx.x * 128;
    const int c0 = blockIdx.y * 64;
    const int wv = t >> 6;
    const int lane = t & 63;
    const int c31 = lane & 31;
    const int hi = lane >> 5;

    const int rb = blockIdx.x * 4 + wv;
    const u16* pA  = Gf + (size_t)rb * 16384 + lane * 8;
    const char* gB = (const char*)(Wf + (size_t)(64 + blockIdx.y * 2) * 16384);

    f16v acc0, acc1;
#pragma unroll
    for (int i = 0; i < 16; ++i) { acc0[i] = 0.f; acc1[i] = 0.f; }

#pragma unroll
    for (int j = 0; j < 16; ++j)
        gld16(smem + j * 4096 + wv * 1024, gB + j * 4096 + t * 16);
    __builtin_amdgcn_sched_barrier(0);

    s8v aA[4], aB[4], aC[4];
#define LOADO(S, KT)                                                      \
    { _Pragma("unroll") for (int ks = 0; ks < 4; ++ks) {                  \
        a##S[ks] = *(const s8v*)(pA + (KT) * 2048 + ks * 512); } }
#define MFMAO(S, KT)                                                                        \
    { const char* bbq = smem + (KT) * 4096;                                                 \
      _Pragma("unroll") for (int ks = 0; ks < 4; ++ks) {                                    \
        s8v b0 = *(const s8v*)(bbq + ks * 1024 + lane * 16);                                \
        s8v b1 = *(const s8v*)(bbq + 32768 + ks * 1024 + lane * 16);                        \
        acc0 = __builtin_amdgcn_mfma_f32_32x32x16_bf16(a##S[ks], b0, acc0, 0, 0, 0);        \
        acc1 = __builtin_amdgcn_mfma_f32_32x32x16_bf16(a##S[ks], b1, acc1, 0, 0, 0); } }
    LOADO(A, 0)
    LOADO(B, 1)
    __builtin_amdgcn_sched_barrier(0);
    asm volatile("s_waitcnt vmcnt(8)" ::: "memory");
    __syncthreads();
    LOADO(C, 2)
    __builtin_amdgcn_sched_barrier(0);
    MFMAO(A, 0)
    LOADO(A, 3)
    __builtin_amdgcn_sched_barrier(0);
    MFMAO(B, 1)
    LOADO(B, 4)
    __builtin_amdgcn_sched_barrier(0);
    MFMAO(C, 2)
    LOADO(C, 5)
    __builtin_amdgcn_sched_barrier(0);
    MFMAO(A, 3)
    LOADO(A, 6)
    __builtin_amdgcn_sched_barrier(0);
    MFMAO(B, 4)
    LOADO(B, 7)
    __builtin_amdgcn_sched_barrier(0);
    MFMAO(C, 5)
    __builtin_amdgcn_sched_barrier(0);
    MFMAO(A, 6)
    __builtin_amdgcn_sched_barrier(0);
    MFMAO(B, 7)
#undef LOADO
#undef MFMAO

#pragma unroll
    for (int n = 0; n < 2; ++n) {
        const f16v acc = n ? acc1 : acc0;
        int C = c0 + n * 32 + c31;
#pragma unroll
        for (int r = 0; r < 16; ++r) {
            int lrow = wv * 32 + (r & 3) + 8 * (r >> 2) + 4 * hi;
            out[(size_t)(l0 + lrow) * DD + C] = acc[r];
        }
    }
}

extern "C" void kernel_launch(void* const* d_in, const int* in_sizes, int n_in,
                              void* d_out, int out_size, void* d_ws, size_t ws_size,
                              hipStream_t stream) {
    const float* X   = (const float*)d_in[0];
    const float* W_Q = (const float*)d_in[1];
    const float* W_K = (const float*)d_in[2];
    const float* W_V = (const float*)d_in[3];
    const float* W_G = (const float*)d_in[4];
    const float* W_O = (const float*)d_in[5];
    const float* gnw = (const float*)d_in[6];
    const float* gnb = (const float*)d_in[7];

    float* ws   = (float*)d_ws;
    u16* qhp  = (u16*)(ws + WS_QH);
    u16* khp  = (u16*)(ws + WS_KH);
    u16* vtp  = (u16*)(ws + WS_VT);
    u16* xfp  = (u16*)(ws + WS_XFH);
    u16* wf   = (u16*)(ws + WS_WF);
    u16* gate16 = (u16*)(ws + WS_GATE);
    float* tab  = ws + WS_TAB;
    u16* ktwp = (u16*)(ws + WS_KTWH);
    float* Abuf = ws + WS_XFH;         // A_state over dead Xf (2M floats, spans XFH+XFL)
    u16* sthp = (u16*)(ws + WS_KTWH);  // St over dead ktw
    u16* Gfp  = (u16*)(ws + WS_XFH);   // frag-packed gg over dead A_state
    float* out  = (float*)d_out;

    k_pre<<<2816, 256, 0, stream>>>(X, W_Q, W_K, W_V, W_G, W_O, tab, xfp, wf);
    k_fused<<<1024, 256, 0, stream>>>(xfp, wf, tab, qhp, khp, vtp, gate16, ktwp);
    k_ret1<<<dim3(64, 8), 256, 0, stream>>>(vtp, ktwp, Abuf);
    k_scan<<<128, 256, 0, stream>>>(Abuf, sthp);
    k_ret3<<<dim3(64, 8), 256, 0, stream>>>(qhp, khp, vtp, sthp, gate16, gnw, gnb, Gfp);
    k_out<<<dim3(32, 8), 256, 0, stream>>>(Gfp, wf, out);
}

// Round 13
// 66.718 us; speedup vs baseline: 1.1294x; 1.0435x over previous
//
#include <hip/hip_runtime.h>
#include <math.h>

#define LQ 4096
#define DD 512
#define NH 8
#define HS 64
#define HALF 32

typedef unsigned short u16;
typedef unsigned int u32;
typedef __attribute__((ext_vector_type(8)))  short s8v;   // 8 x bf16 (MFMA A/B frag)
typedef __attribute__((ext_vector_type(4)))  float f4v;
typedef __attribute__((ext_vector_type(4)))  u32  u32x4;
typedef __attribute__((ext_vector_type(16))) float f16v;  // 32x32 MFMA C/D

// workspace offsets (in floats)
#define WS_QH   0u
#define WS_KH   2097152u
#define WS_KL   3145728u    // unused
#define WS_VT   4194304u
#define WS_XFH  5242880u    // frag-packed X (bf16); later A_state spans XFH+XFL; later Gf
#define WS_XFL  6291456u
#define WS_WF   7340032u    // frag-packed W bf16
#define WS_GATE 8650752u    // gate bf16
#define WS_TAB  10747904u
#define WS_KTWH 11272192u   // ktw; later St

__device__ inline u16 f2bf(float x) {
    unsigned int u = __float_as_uint(x);
    return (u16)((u + 0x7fffu + ((u >> 16) & 1u)) >> 16);
}
__device__ inline float bf2f(u16 h) { return __uint_as_float(((unsigned int)h) << 16); }

__device__ __forceinline__ void gld16(void* lds, const void* g) {
    __builtin_amdgcn_global_load_lds(
        (const __attribute__((address_space(1))) void*)g,
        (__attribute__((address_space(3))) void*)lds, 16, 0, 0);
}

// ---------------- merged prep: xPos tables (LDS LUT) | X->frag bf16 | W->frag bf16 ----------------
__global__ __launch_bounds__(256) void k_pre(
    const float* __restrict__ X,
    const float* __restrict__ Wq, const float* __restrict__ Wk, const float* __restrict__ Wv,
    const float* __restrict__ Wg, const float* __restrict__ Wo,
    float* __restrict__ tab, u16* __restrict__ Xf, u16* __restrict__ Wf) {
    __shared__ float tile[32][33];
    __shared__ double dlut[32];   // invf[i], double (theta needs full precision)
    __shared__ float  flut[32];   // log2(sv)[i]
    const int b = blockIdx.x;
    const int t = threadIdx.x;
    if (b < 512) {
        if (t < 32) {
            dlut[t] = exp2((double)t * (-13.287712379549449 / 32.0));
            flut[t] = (float)log2((2.0 * t + 25.6) / 89.6);
        }
        __syncthreads();
        int idx = b * 256 + t;        // exactly LQ*HALF threads total
        int l = idx >> 5;
        int i = idx & 31;
        float e = (float)l * flut[i] * (1.0f / 512.0f);
        float sc  = exp2f(e);
        float sci = exp2f(-e);
        double th = (double)l * dlut[i];
        double r = th - 6.283185307179586 * floor(th * 0.15915494309189535);
        float c = cosf((float)r), sn = sinf((float)r);
        tab[idx]                 = c * sc;
        tab[LQ*HALF + idx]       = sn * sc;
        tab[2*LQ*HALF + idx]     = c * sci;
        tab[3*LQ*HALF + idx]     = sn * sci;
    } else if (b < 1536) {
        // X -> fragment-packed bf16: Xf[rb:128][kt:8][ks:4][lane:64][8]
        int g = (b - 512) * 256 + t;
        int l = g >> 6;
        int d = (g & 63) * 8;
        const float* xp = X + (size_t)l * DD + d;
        f4v x0 = *(const f4v*)xp;
        f4v x1 = *(const f4v*)(xp + 4);
        s8v ph;
#pragma unroll
        for (int j = 0; j < 4; ++j) {
            ph[j]   = (short)f2bf(x0[j]);
            ph[j+4] = (short)f2bf(x1[j]);
        }
        int rb = l >> 5, kt = d >> 6, ks = (d >> 4) & 3, kh2 = (d >> 3) & 1;
        int lane = kh2 * 32 + (l & 31);
        size_t off = (((size_t)(rb * 8 + kt) * 4 + ks) * 64 + lane) * 8;
        *(s8v*)(Xf + off) = ph;
    } else {
        // weights -> fragment-packed bf16: Wf[nb:80][kt:8][ks:4][lane:64][8]
        int bb = b - 1536;
        int d0 = (bb & 15) * 32, C0 = (bb >> 4) * 32;
        int proj = C0 >> 9;
        int tc = t & 31, tr = t >> 5;
#pragma unroll
        for (int rr = 0; rr < 4; ++rr) {
            int dl = tr + rr * 8;
            int d = d0 + dl;
            int C = C0 + tc;
            float val;
            if (proj < 3) {
                const float* W = (proj == 0) ? Wq : ((proj == 1) ? Wk : Wv);
                int h = (C & 511) >> 6, hs = C & 63;
                val = W[(size_t)h * (DD * HS) + (size_t)d * HS + hs];
            } else if (proj == 3) {
                val = Wg[(size_t)d * DD + (C & 511)];
            } else {
                val = Wo[(size_t)d * DD + (C - 2048)];
            }
            tile[dl][tc] = val;
        }
        __syncthreads();
        if (t < 128) {
            int cl = t & 31, dgq = t >> 5;
            int dl = dgq * 8;
            s8v pk;
#pragma unroll
            for (int j = 0; j < 8; ++j) pk[j] = (short)f2bf(tile[dl + j][cl]);
            int C = C0 + cl;
            int da = d0 + dl;
            int nb = C >> 5, kt = da >> 6, ks = (da >> 4) & 3, kh2 = (da >> 3) & 1;
            int lane = kh2 * 32 + (C & 31);
            size_t off = (((size_t)(nb * 8 + kt) * 4 + ks) * 64 + lane) * 8;
            *(s8v*)(Wf + off) = pk;
        }
    }
}

// ---------------- fused MFMA GEMM: A frag-direct pinned, B LDS-shared (2 phases) [R10] ----------------
// grid 1024 (chunked XCD swizzle), block 256 (4 waves, each 32l x 64c).
__global__ __launch_bounds__(256) void k_fused(
    const u16* __restrict__ Xf, const u16* __restrict__ Wf,
    const float* __restrict__ tab,
    u16* __restrict__ qh, u16* __restrict__ kh,
    u16* __restrict__ vt, u16* __restrict__ gate16,
    u16* __restrict__ ktw) {
    __shared__ __align__(16) char smem[33024];   // B stage 32KB; vbuf alias after loop
    const int t = threadIdx.x;
    const int b = blockIdx.x;
    const int mb = (b & 7) * 4 + (b >> 8);   // 0..31
    const int cb = (b >> 3) & 31;            // 0..31
    const int l0 = mb * 128;
    const int c0 = cb * 64;
    const int wv = t >> 6;
    const int lane = t & 63;
    const int c31 = lane & 31;
    const int hi = lane >> 5;

    const int rb = mb * 4 + wv;
    const u16* pA = Xf + (size_t)rb * 16384 + lane * 8;
    const char* gB = (const char*)(Wf + (size_t)(cb * 2) * 16384);

    f16v acc0, acc1;
#pragma unroll
    for (int i = 0; i < 16; ++i) { acc0[i] = 0.f; acc1[i] = 0.f; }

#define STAGEB(PH)                                                             \
    { _Pragma("unroll") for (int j = 0; j < 8; ++j) {                          \
        int seg = j >> 2, q4 = j & 3;                                          \
        gld16(smem + seg * 16384 + q4 * 4096 + wv * 1024,                      \
              gB + seg * 32768 + (PH) * 16384 + q4 * 4096 + t * 16); } }
    s8v aA[4], aB[4];
#define LOADA(S, KT)                                                      \
    { _Pragma("unroll") for (int ks = 0; ks < 4; ++ks) {                  \
        a##S[ks] = *(const s8v*)(pA + (KT) * 2048 + ks * 512); } }
#define MFMAX(S, KT)                                                                        \
    { const char* bbq = smem + ((KT) & 3) * 4096;                                           \
      _Pragma("unroll") for (int ks = 0; ks < 4; ++ks) {                                    \
        s8v b0 = *(const s8v*)(bbq + ks * 1024 + lane * 16);                                \
        s8v b1 = *(const s8v*)(bbq + 16384 + ks * 1024 + lane * 16);                        \
        acc0 = __builtin_amdgcn_mfma_f32_32x32x16_bf16(a##S[ks], b0, acc0, 0, 0, 0);        \
        acc1 = __builtin_amdgcn_mfma_f32_32x32x16_bf16(a##S[ks], b1, acc1, 0, 0, 0); } }
    STAGEB(0)
    LOADA(A, 0)
    asm volatile("s_waitcnt vmcnt(0)" ::: "memory");
    __syncthreads();
    LOADA(B, 1)
    __builtin_amdgcn_sched_barrier(0);
    MFMAX(A, 0)
    LOADA(A, 2)
    __builtin_amdgcn_sched_barrier(0);
    MFMAX(B, 1)
    LOADA(B, 3)
    __builtin_amdgcn_sched_barrier(0);
    MFMAX(A, 2)
    LOADA(A, 4)
    __builtin_amdgcn_sched_barrier(0);
    MFMAX(B, 3)
    __syncthreads();                 // all waves done reading phase-0 B
    STAGEB(1)
    asm volatile("s_waitcnt vmcnt(0)" ::: "memory");
    __syncthreads();
    LOADA(B, 5)
    __builtin_amdgcn_sched_barrier(0);
    MFMAX(A, 4)
    LOADA(A, 6)
    __builtin_amdgcn_sched_barrier(0);
    MFMAX(B, 5)
    LOADA(B, 7)
    __builtin_amdgcn_sched_barrier(0);
    MFMAX(A, 6)
    __builtin_amdgcn_sched_barrier(0);
    MFMAX(B, 7)
#undef LOADA
#undef MFMAX
#undef STAGEB
    __syncthreads();                     // B LDS dead; safe to alias vbuf below

    float* vbuf = (float*)smem;          // [64][129] f32
    const int proj = c0 >> 9;
    if (proj < 2) {
        const float* ct = tab + (proj ? 2 * LQ * HALF : 0);
        const float* st = tab + (proj ? 3 * LQ * HALF : LQ * HALF);
        u16* oh = proj ? kh : qh;
        const int hh = (c0 & 511) >> 6;
        float lgf = 0.f;
        if (proj == 1) {
            double lg = -3.4657359027997265 + (double)hh * (-2.772588722239781 / 7.0);
            lgf = (float)(log(1.0 - exp(lg)) * 1.4426950408889634);
        }
#pragma unroll
        for (int n = 0; n < 2; ++n) {
            const f16v acc = n ? acc1 : acc0;
            int C = c0 + n * 32 + c31;
            int hs = C & 63, i2 = hs >> 1;
            float sgn = (hs & 1) ? 1.f : -1.f;
#pragma unroll
            for (int r = 0; r < 16; ++r) {
                int lrow = wv * 32 + (r & 3) + 8 * (r >> 2) + 4 * hi;
                int pos = l0 + lrow;
                float val = acc[r];
                float part = __shfl_xor(val, 1);
                float res = val * ct[pos * HALF + i2] + sgn * part * st[pos * HALF + i2];
                size_t o = ((size_t)hh * LQ + pos) * HS + hs;
                oh[o] = f2bf(res);
                if (proj == 1) {
                    float wf = exp2f(lgf * (float)(64 - (pos & 63)));   // gamma^(64-m')
                    vbuf[(n * 32 + c31) * 129 + lrow] = res * wf;
                }
            }
        }
        if (proj == 1) {
            __syncthreads();
            int cl = t >> 2, lseg = (t & 3) * 32;
            size_t o = ((size_t)hh * HS + cl) * LQ + l0 + lseg;
#pragma unroll
            for (int ch4 = 0; ch4 < 4; ++ch4) {
                s8v pkh;
#pragma unroll
                for (int j = 0; j < 8; ++j) pkh[j] = (short)f2bf(vbuf[cl * 129 + lseg + ch4 * 8 + j]);
                *(s8v*)(ktw + o + ch4 * 8) = pkh;
            }
        }
    } else if (proj == 2) {
#pragma unroll
        for (int n = 0; n < 2; ++n) {
            const f16v acc = n ? acc1 : acc0;
            int cl = n * 32 + c31;
#pragma unroll
            for (int r = 0; r < 16; ++r) {
                int lrow = wv * 32 + (r & 3) + 8 * (r >> 2) + 4 * hi;
                vbuf[cl * 129 + lrow] = acc[r];
            }
        }
        __syncthreads();
        int h = (c0 & 511) >> 6;
        int cl = t >> 2, lseg = (t & 3) * 32;
        size_t o = ((size_t)h * HS + cl) * LQ + l0 + lseg;
#pragma unroll
        for (int ch = 0; ch < 4; ++ch) {
            s8v pk;
#pragma unroll
            for (int j = 0; j < 8; ++j) pk[j] = (short)f2bf(vbuf[cl * 129 + lseg + ch * 8 + j]);
            *(s8v*)(vt + o + ch * 8) = pk;
        }
    } else {
#pragma unroll
        for (int n = 0; n < 2; ++n) {
            const f16v acc = n ? acc1 : acc0;
            int C = (c0 & 511) + n * 32 + c31;
#pragma unroll
            for (int r = 0; r < 16; ++r) {
                int lrow = wv * 32 + (r & 3) + 8 * (r >> 2) + 4 * hi;
                float vv = acc[r];
                gate16[(size_t)(l0 + lrow) * DD + C] = f2bf(vv / (1.f + expf(-vv)));
            }
        }
    }
}

// ---------------- pass1: per-chunk state A^T[ch][d], 4 waves/chunk ----------------
__global__ __launch_bounds__(256) void k_ret1(
    const u16* __restrict__ vt, const u16* __restrict__ ktw,
    float* __restrict__ A) {
    const int t = threadIdx.x;
    const int c = blockIdx.x;
    const int h = blockIdx.y;
    const int wv = t >> 6, lane = t & 63, c31 = lane & 31, hi = lane >> 5;
    const int wch = wv >> 1, wd = wv & 1;

    s8v va[4];
    const u16* vp = vt + ((size_t)h * 64 + wch * 32 + c31) * LQ + c * 64 + hi * 8;
#pragma unroll
    for (int ks = 0; ks < 4; ++ks) va[ks] = *(const s8v*)(vp + ks * 16);

    f16v a;
#pragma unroll
    for (int i = 0; i < 16; ++i) a[i] = 0.f;

    const size_t kbase = ((size_t)h * 64 + wd * 32 + c31) * LQ + c * 64 + hi * 8;
#pragma unroll
    for (int ks = 0; ks < 4; ++ks) {
        s8v b_h = *(const s8v*)(ktw + kbase + ks * 16);
        a = __builtin_amdgcn_mfma_f32_32x32x16_bf16(va[ks], b_h, a, 0, 0, 0);
    }

    float* Ab = A + ((size_t)h * 64 + c) * 4096;
#pragma unroll
    for (int r = 0; r < 16; ++r) {
        int ch = wch * 32 + (r & 3) + 8 * (r >> 2) + 4 * hi;
        Ab[ch * 64 + wd * 32 + c31] = a[r];
    }
}

// ---------------- pass2: weighted prefix scan over chunks -> S^T bf16 ----------------
__global__ __launch_bounds__(256) void k_scan(
    const float* __restrict__ A, u16* __restrict__ sth) {
    const int bx = blockIdx.x;
    const int h = bx >> 4;
    const int e = (bx & 15) * 256 + threadIdx.x;
    double lg = -3.4657359027997265 + (double)h * (-2.772588722239781 / 7.0);
    double gamma = 1.0 - exp(lg);
    float g64 = (float)pow(gamma, 64.0);
    const float* Ab = A + (size_t)h * 64 * 4096 + e;
    u16* shb = sth + (size_t)h * 64 * 4096 + e;
    float av[64];
#pragma unroll
    for (int cc = 0; cc < 64; ++cc) av[cc] = Ab[(size_t)cc * 4096];
    float s = 0.f;
#pragma unroll
    for (int cc = 0; cc < 64; ++cc) {
        if (cc) shb[(size_t)cc * 4096] = f2bf(s);
        s = fmaf(g64, s, av[cc]);
    }
}

// ---------------- pass3: retention chunk + fused GroupNorm*gate -> frag-packed gg ----------------
// grid (64, 8), block 256 (4 waves). wave = (ws = row strip, wc = output col half).
__global__ __launch_bounds__(256) void k_ret3(
    const u16* __restrict__ qh, const u16* __restrict__ kh,
    const u16* __restrict__ vt, const u16* __restrict__ sth,
    const u16* __restrict__ gate16,
    const float* __restrict__ gw, const float* __restrict__ gb,
    u16* __restrict__ Gf) {
    __shared__ __align__(16) char sBuf[16640];   // KH 8K | VT 8K; later gT[64][65] f32
    __shared__ float stats[64][2][2];            // [row][wc][s,ss]
    const int t = threadIdx.x;
    const int c = blockIdx.x;
    const int h = blockIdx.y;
    const int wv = t >> 6, lane = t & 63, c31 = lane & 31, hi = lane >> 5;
    const int ws = wv >> 1, wc = wv & 1;
    const int l0q = c * 64;

    double lg = -3.4657359027997265 + (double)h * (-2.772588722239781 / 7.0);
    double gamma = 1.0 - exp(lg);
    float lgf = (float)(log(gamma) * 1.4426950408889634);
    float c1a[4], c8a[4];
#pragma unroll
    for (int m = 0; m < 4; ++m) { c1a[m] = exp2f(-lgf * (float)m); c8a[m] = exp2f(-lgf * (float)(8 * m)); }

    // Q fragments for this wave's row strip
    s8v qhf[4];
    {
        const u16* qph = qh + ((size_t)h * LQ + l0q + ws * 32 + c31) * HS + hi * 8;
#pragma unroll
        for (int ks = 0; ks < 4; ++ks) qhf[ks] = *(const s8v*)(qph + ks * 16);
    }

    // stage K + VT (pre-swizzled source, linear LDS dest), 4 x 16B per thread
    {
        const char* gKH = (const char*)kh + ((size_t)h * LQ + l0q) * 128;
        const char* gVT = (const char*)vt + ((size_t)h * 64) * 8192 + l0q * 2;
#pragma unroll
        for (int i_ = 0; i_ < 4; ++i_) {
            int boff = i_ * 4096 + t * 16;
            int seg = boff >> 13;
            int o_ = boff & 8191;
            int osrc = o_ ^ (((o_ >> 7) & 7) << 4);
            const char* src = (seg == 0) ? gKH + osrc
                            : gVT + (size_t)(osrc >> 7) * 8192 + (osrc & 127);
            gld16(sBuf + i_ * 4096 + (t >> 6) * 1024, src);
        }
    }

    // inter-chunk: qs = Q @ S^T for this wave's col half
    f16v qs;
#pragma unroll
    for (int i = 0; i < 16; ++i) qs[i] = 0.f;
    if (c > 0) {
        const u16* sbh = sth + ((size_t)h * 64 + c) * 4096;
#pragma unroll
        for (int ks = 0; ks < 4; ++ks) {
            int off = (wc * 32 + c31) * 64 + ks * 16 + hi * 8;
            s8v b_h = *(const s8v*)(sbh + off);
            qs = __builtin_amdgcn_mfma_f32_32x32x16_bf16(qhf[ks], b_h, qs, 0, 0, 0);
        }
    }

    asm volatile("s_waitcnt vmcnt(0)" ::: "memory");
    __syncthreads();

    // intra-chunk masked tile (QK^T duplicated across wc; PV split by wc)
    f16v acc;
#pragma unroll
    for (int i = 0; i < 16; ++i) acc[i] = 0.f;
    const char* bKH = sBuf;
    const char* bVT = sBuf + 8192;

#pragma unroll
    for (int jt = 0; jt < 2; ++jt) {
        if (ws == 0 && jt == 1) break;
        f16v sacc;
#pragma unroll
        for (int i = 0; i < 16; ++i) sacc[i] = 0.f;
#pragma unroll
        for (int ks = 0; ks < 4; ++ks) {
            int krow = jt * 32 + c31;
            int ph = krow * 128 + ((ks * 32 + hi * 16) ^ ((krow & 7) << 4));
            s8v ah = *(const s8v*)(bKH + ph);
            sacc = __builtin_amdgcn_mfma_f32_32x32x16_bf16(ah, qhf[ks], sacc, 0, 0, 0);
        }
        const int D0 = (ws * 32 + c31) - jt * 32;
        float base = exp2f(lgf * (float)(D0 - 4 * hi));
        u32 w[8];
#pragma unroll
        for (int g = 0; g < 4; ++g) {
            float wg = base * c8a[g];
            float v0 = sacc[4 * g + 0] * (wg * c1a[0]);
            float v1 = sacc[4 * g + 1] * (wg * c1a[1]);
            float v2 = sacc[4 * g + 2] * (wg * c1a[2]);
            float v3 = sacc[4 * g + 3] * (wg * c1a[3]);
            int jr = 8 * g + 4 * hi;
            if (D0 - (jr + 0) < 0) v0 = 0.f;
            if (D0 - (jr + 1) < 0) v1 = 0.f;
            if (D0 - (jr + 2) < 0) v2 = 0.f;
            if (D0 - (jr + 3) < 0) v3 = 0.f;
            w[2 * g]     = (u32)f2bf(v0) | ((u32)f2bf(v1) << 16);
            w[2 * g + 1] = (u32)f2bf(v2) | ((u32)f2bf(v3) << 16);
        }
        u32 e0 = __shfl_xor(hi ? w[0] : w[2], 32);
        u32 e1 = __shfl_xor(hi ? w[1] : w[3], 32);
        u32 e2 = __shfl_xor(hi ? w[4] : w[6], 32);
        u32 e3 = __shfl_xor(hi ? w[5] : w[7], 32);
        u32x4 a0v = { hi ? e0 : w[0], hi ? e1 : w[1], hi ? w[2] : e0, hi ? w[3] : e1 };
        u32x4 a1v = { hi ? e2 : w[4], hi ? e3 : w[5], hi ? w[6] : e2, hi ? w[7] : e3 };
        s8v af0 = __builtin_bit_cast(s8v, a0v);
        s8v af1 = __builtin_bit_cast(s8v, a1v);
#pragma unroll
        for (int ksl = 0; ksl < 2; ++ksl) {
            s8v af = ksl ? af1 : af0;
            int cb = (jt * 2 + ksl) * 32 + hi * 16;
            int rv = wc * 32 + c31;
            s8v vb = *(const s8v*)(bVT + rv * 128 + (cb ^ ((rv & 7) << 4)));
            acc = __builtin_amdgcn_mfma_f32_32x32x16_bf16(af, vb, acc, 0, 0, 0);
        }
    }

    // epilogue: combine inter+intra; cross-wc GroupNorm stats via LDS; *gate; frag-pack gg
    float vv[16];
#pragma unroll
    for (int r = 0; r < 16; ++r) {
        int row = (r & 3) + 8 * (r >> 2) + 4 * hi;
        int nloc = ws * 32 + row;
        float sc = exp2f(lgf * (float)nloc);
        vv[r] = acc[r] + sc * qs[r];
    }
#pragma unroll
    for (int r = 0; r < 16; ++r) {
        float s = vv[r], ss = vv[r] * vv[r];
#pragma unroll
        for (int off = 1; off < 32; off <<= 1) {
            s  += __shfl_xor(s, off);
            ss += __shfl_xor(ss, off);
        }
        if (c31 == 0) {
            int nloc = ws * 32 + (r & 3) + 8 * (r >> 2) + 4 * hi;
            stats[nloc][wc][0] = s;
            stats[nloc][wc][1] = ss;
        }
    }
    __syncthreads();   // stats ready; all sBuf (K/V) reads also done -> safe to alias gT

    float* gT = (float*)sBuf;           // [64][65] f32
    const float gwv = gw[h * HS + wc * 32 + c31];
    const float gbv = gb[h * HS + wc * 32 + c31];
#pragma unroll
    for (int r = 0; r < 16; ++r) {
        int nloc = ws * 32 + (r & 3) + 8 * (r >> 2) + 4 * hi;
        float s  = stats[nloc][0][0] + stats[nloc][1][0];
        float ss = stats[nloc][0][1] + stats[nloc][1][1];
        float mean = s * (1.f / 64.f);
        float var = ss * (1.f / 64.f) - mean * mean;
        float inv = rsqrtf(var + 1e-5f);
        size_t o = (size_t)(l0q + nloc) * DD + h * HS + wc * 32 + c31;
        float g = ((vv[r] - mean) * inv * gwv + gbv) * bf2f(gate16[o]);
        gT[nloc * 65 + wc * 32 + c31] = g;
    }
    __syncthreads();
#pragma unroll
    for (int i = 0; i < 2; ++i) {
        int u = t + i * 256;            // 0..511
        int rbl = u >> 8;
        int ks = (u >> 6) & 3;
        int ln = u & 63;
        int row = rbl * 32 + (ln & 31);
        int ch = ks * 16 + (ln >> 5) * 8;
        s8v pk;
#pragma unroll
        for (int j = 0; j < 8; ++j) pk[j] = (short)f2bf(gT[row * 65 + ch + j]);
        size_t off = ((((size_t)(c * 2 + rbl) * 8 + h) * 4 + ks) * 64 + ln) * 8;
        *(s8v*)(Gf + off) = pk;
    }
}

// ---------------- out = gg @ W_O (A frag-direct pinned, B LDS-shared 2 phases) [R10] ----------------
__global__ __launch_bounds__(256) void k_out(
    const u16* __restrict__ Gf, const u16* __restrict__ Wf,
    float* __restrict__ out) {
    __shared__ __align__(16) char smem[32768];
    const int t = threadIdx.x;
    const int l0 = blockIdx.x * 128;
    const int c0 = blockIdx.y * 64;
    const int wv = t >> 6;
    const int lane = t & 63;
    const int c31 = lane & 31;
    const int hi = lane >> 5;

    const int rb = blockIdx.x * 4 + wv;
    const u16* pA  = Gf + (size_t)rb * 16384 + lane * 8;
    const char* gB = (const char*)(Wf + (size_t)(64 + blockIdx.y * 2) * 16384);

    f16v acc0, acc1;
#pragma unroll
    for (int i = 0; i < 16; ++i) { acc0[i] = 0.f; acc1[i] = 0.f; }

#define STAGEB(PH)                                                             \
    { _Pragma("unroll") for (int j = 0; j < 8; ++j) {                          \
        int seg = j >> 2, q4 = j & 3;                                          \
        gld16(smem + seg * 16384 + q4 * 4096 + wv * 1024,                      \
              gB + seg * 32768 + (PH) * 16384 + q4 * 4096 + t * 16); } }
    s8v aA[4], aB[4];
#define LOADO(S, KT)                                                      \
    { _Pragma("unroll") for (int ks = 0; ks < 4; ++ks) {                  \
        a##S[ks] = *(const s8v*)(pA + (KT) * 2048 + ks * 512); } }
#define MFMAO(S, KT)                                                                        \
    { const char* bbq = smem + ((KT) & 3) * 4096;                                           \
      _Pragma("unroll") for (int ks = 0; ks < 4; ++ks) {                                    \
        s8v b0 = *(const s8v*)(bbq + ks * 1024 + lane * 16);                                \
        s8v b1 = *(const s8v*)(bbq + 16384 + ks * 1024 + lane * 16);                        \
        acc0 = __builtin_amdgcn_mfma_f32_32x32x16_bf16(a##S[ks], b0, acc0, 0, 0, 0);        \
        acc1 = __builtin_amdgcn_mfma_f32_32x32x16_bf16(a##S[ks], b1, acc1, 0, 0, 0); } }
    STAGEB(0)
    LOADO(A, 0)
    asm volatile("s_waitcnt vmcnt(0)" ::: "memory");
    __syncthreads();
    LOADO(B, 1)
    __builtin_amdgcn_sched_barrier(0);
    MFMAO(A, 0)
    LOADO(A, 2)
    __builtin_amdgcn_sched_barrier(0);
    MFMAO(B, 1)
    LOADO(B, 3)
    __builtin_amdgcn_sched_barrier(0);
    MFMAO(A, 2)
    LOADO(A, 4)
    __builtin_amdgcn_sched_barrier(0);
    MFMAO(B, 3)
    __syncthreads();
    STAGEB(1)
    asm volatile("s_waitcnt vmcnt(0)" ::: "memory");
    __syncthreads();
    LOADO(B, 5)
    __builtin_amdgcn_sched_barrier(0);
    MFMAO(A, 4)
    LOADO(A, 6)
    __builtin_amdgcn_sched_barrier(0);
    MFMAO(B, 5)
    LOADO(B, 7)
    __builtin_amdgcn_sched_barrier(0);
    MFMAO(A, 6)
    __builtin_amdgcn_sched_barrier(0);
    MFMAO(B, 7)
#undef LOADO
#undef MFMAO
#undef STAGEB

#pragma unroll
    for (int n = 0; n < 2; ++n) {
        const f16v acc = n ? acc1 : acc0;
        int C = c0 + n * 32 + c31;
#pragma unroll
        for (int r = 0; r < 16; ++r) {
            int lrow = wv * 32 + (r & 3) + 8 * (r >> 2) + 4 * hi;
            out[(size_t)(l0 + lrow) * DD + C] = acc[r];
        }
    }
}

extern "C" void kernel_launch(void* const* d_in, const int* in_sizes, int n_in,
                              void* d_out, int out_size, void* d_ws, size_t ws_size,
                              hipStream_t stream) {
    const float* X   = (const float*)d_in[0];
    const float* W_Q = (const float*)d_in[1];
    const float* W_K = (const float*)d_in[2];
    const float* W_V = (const float*)d_in[3];
    const float* W_G = (const float*)d_in[4];
    const float* W_O = (const float*)d_in[5];
    const float* gnw = (const float*)d_in[6];
    const float* gnb = (const float*)d_in[7];

    float* ws   = (float*)d_ws;
    u16* qhp  = (u16*)(ws + WS_QH);
    u16* khp  = (u16*)(ws + WS_KH);
    u16* vtp  = (u16*)(ws + WS_VT);
    u16* xfp  = (u16*)(ws + WS_XFH);
    u16* wf   = (u16*)(ws + WS_WF);
    u16* gate16 = (u16*)(ws + WS_GATE);
    float* tab  = ws + WS_TAB;
    u16* ktwp = (u16*)(ws + WS_KTWH);
    float* Abuf = ws + WS_XFH;         // A_state over dead Xf (2M floats, spans XFH+XFL)
    u16* sthp = (u16*)(ws + WS_KTWH);  // St over dead ktw
    u16* Gfp  = (u16*)(ws + WS_XFH);   // frag-packed gg over dead A_state
    float* out  = (float*)d_out;

    k_pre<<<2816, 256, 0, stream>>>(X, W_Q, W_K, W_V, W_G, W_O, tab, xfp, wf);
    k_fused<<<1024, 256, 0, stream>>>(xfp, wf, tab, qhp, khp, vtp, gate16, ktwp);
    k_ret1<<<dim3(64, 8), 256, 0, stream>>>(vtp, ktwp, Abuf);
    k_scan<<<128, 256, 0, stream>>>(Abuf, sthp);
    k_ret3<<<dim3(64, 8), 256, 0, stream>>>(qhp, khp, vtp, sthp, gate16, gnw, gnb, Gfp);
    k_out<<<dim3(32, 8), 256, 0, stream>>>(Gfp, wf, out);
}

// Round 14
// 64.990 us; speedup vs baseline: 1.1595x; 1.0266x over previous
//
#include <hip/hip_runtime.h>
#include <math.h>

#define LQ 4096
#define DD 512
#define NH 8
#define HS 64
#define HALF 32

typedef unsigned short u16;
typedef unsigned int u32;
typedef __attribute__((ext_vector_type(8)))  short s8v;   // 8 x bf16 (MFMA A/B frag)
typedef __attribute__((ext_vector_type(4)))  float f4v;
typedef __attribute__((ext_vector_type(4)))  u32  u32x4;
typedef __attribute__((ext_vector_type(16))) float f16v;  // 32x32 MFMA C/D

// workspace offsets (in floats)
#define WS_QH   0u
#define WS_KH   2097152u
#define WS_KL   3145728u    // unused
#define WS_VT   4194304u
#define WS_XFH  5242880u    // frag-packed X (bf16); later A_state (bf16); later Gf
#define WS_XFL  6291456u
#define WS_WF   7340032u    // frag-packed W bf16
#define WS_GATE 8650752u    // gate bf16
#define WS_TAB  10747904u
#define WS_KTWH 11272192u   // ktw; later St

__device__ inline u16 f2bf(float x) {
    unsigned int u = __float_as_uint(x);
    return (u16)((u + 0x7fffu + ((u >> 16) & 1u)) >> 16);
}
__device__ inline float bf2f(u16 h) { return __uint_as_float(((unsigned int)h) << 16); }

__device__ __forceinline__ void gld16(void* lds, const void* g) {
    __builtin_amdgcn_global_load_lds(
        (const __attribute__((address_space(1))) void*)g,
        (__attribute__((address_space(3))) void*)lds, 16, 0, 0);
}

// ---------------- merged prep: xPos tables (LDS LUT) | X->frag bf16 | W->frag bf16 ----------------
__global__ __launch_bounds__(256) void k_pre(
    const float* __restrict__ X,
    const float* __restrict__ Wq, const float* __restrict__ Wk, const float* __restrict__ Wv,
    const float* __restrict__ Wg, const float* __restrict__ Wo,
    float* __restrict__ tab, u16* __restrict__ Xf, u16* __restrict__ Wf) {
    __shared__ float tile[32][33];
    __shared__ double dlut[32];   // invf[i], double (theta needs full precision)
    __shared__ float  flut[32];   // log2(sv)[i]
    const int b = blockIdx.x;
    const int t = threadIdx.x;
    if (b < 512) {
        if (t < 32) {
            dlut[t] = exp2((double)t * (-13.287712379549449 / 32.0));
            flut[t] = (float)log2((2.0 * t + 25.6) / 89.6);
        }
        __syncthreads();
        int idx = b * 256 + t;        // exactly LQ*HALF threads total
        int l = idx >> 5;
        int i = idx & 31;
        float e = (float)l * flut[i] * (1.0f / 512.0f);
        float sc  = exp2f(e);
        float sci = exp2f(-e);
        double th = (double)l * dlut[i];
        double r = th - 6.283185307179586 * floor(th * 0.15915494309189535);
        float c = cosf((float)r), sn = sinf((float)r);
        tab[idx]                 = c * sc;
        tab[LQ*HALF + idx]       = sn * sc;
        tab[2*LQ*HALF + idx]     = c * sci;
        tab[3*LQ*HALF + idx]     = sn * sci;
    } else if (b < 1536) {
        // X -> fragment-packed bf16: Xf[rb:128][kt:8][ks:4][lane:64][8]
        int g = (b - 512) * 256 + t;
        int l = g >> 6;
        int d = (g & 63) * 8;
        const float* xp = X + (size_t)l * DD + d;
        f4v x0 = *(const f4v*)xp;
        f4v x1 = *(const f4v*)(xp + 4);
        s8v ph;
#pragma unroll
        for (int j = 0; j < 4; ++j) {
            ph[j]   = (short)f2bf(x0[j]);
            ph[j+4] = (short)f2bf(x1[j]);
        }
        int rb = l >> 5, kt = d >> 6, ks = (d >> 4) & 3, kh2 = (d >> 3) & 1;
        int lane = kh2 * 32 + (l & 31);
        size_t off = (((size_t)(rb * 8 + kt) * 4 + ks) * 64 + lane) * 8;
        *(s8v*)(Xf + off) = ph;
    } else {
        // weights -> fragment-packed bf16: Wf[nb:80][kt:8][ks:4][lane:64][8]
        int bb = b - 1536;
        int d0 = (bb & 15) * 32, C0 = (bb >> 4) * 32;
        int proj = C0 >> 9;
        int tc = t & 31, tr = t >> 5;
#pragma unroll
        for (int rr = 0; rr < 4; ++rr) {
            int dl = tr + rr * 8;
            int d = d0 + dl;
            int C = C0 + tc;
            float val;
            if (proj < 3) {
                const float* W = (proj == 0) ? Wq : ((proj == 1) ? Wk : Wv);
                int h = (C & 511) >> 6, hs = C & 63;
                val = W[(size_t)h * (DD * HS) + (size_t)d * HS + hs];
            } else if (proj == 3) {
                val = Wg[(size_t)d * DD + (C & 511)];
            } else {
                val = Wo[(size_t)d * DD + (C - 2048)];
            }
            tile[dl][tc] = val;
        }
        __syncthreads();
        if (t < 128) {
            int cl = t & 31, dgq = t >> 5;
            int dl = dgq * 8;
            s8v pk;
#pragma unroll
            for (int j = 0; j < 8; ++j) pk[j] = (short)f2bf(tile[dl + j][cl]);
            int C = C0 + cl;
            int da = d0 + dl;
            int nb = C >> 5, kt = da >> 6, ks = (da >> 4) & 3, kh2 = (da >> 3) & 1;
            int lane = kh2 * 32 + (C & 31);
            size_t off = (((size_t)(nb * 8 + kt) * 4 + ks) * 64 + lane) * 8;
            *(s8v*)(Wf + off) = pk;
        }
    }
}

// ---------------- fused MFMA GEMM: A frag-direct pinned, B LDS-shared (2 phases) [R10] ----------------
// grid 1024 (chunked XCD swizzle), block 256 (4 waves, each 32l x 64c).
__global__ __launch_bounds__(256) void k_fused(
    const u16* __restrict__ Xf, const u16* __restrict__ Wf,
    const float* __restrict__ tab,
    u16* __restrict__ qh, u16* __restrict__ kh,
    u16* __restrict__ vt, u16* __restrict__ gate16,
    u16* __restrict__ ktw) {
    __shared__ __align__(16) char smem[33024];   // B stage 32KB; vbuf alias after loop
    const int t = threadIdx.x;
    const int b = blockIdx.x;
    const int mb = (b & 7) * 4 + (b >> 8);   // 0..31
    const int cb = (b >> 3) & 31;            // 0..31
    const int l0 = mb * 128;
    const int c0 = cb * 64;
    const int wv = t >> 6;
    const int lane = t & 63;
    const int c31 = lane & 31;
    const int hi = lane >> 5;

    const int rb = mb * 4 + wv;
    const u16* pA = Xf + (size_t)rb * 16384 + lane * 8;
    const char* gB = (const char*)(Wf + (size_t)(cb * 2) * 16384);

    f16v acc0, acc1;
#pragma unroll
    for (int i = 0; i < 16; ++i) { acc0[i] = 0.f; acc1[i] = 0.f; }

#define STAGEB(PH)                                                             \
    { _Pragma("unroll") for (int j = 0; j < 8; ++j) {                          \
        int seg = j >> 2, q4 = j & 3;                                          \
        gld16(smem + seg * 16384 + q4 * 4096 + wv * 1024,                      \
              gB + seg * 32768 + (PH) * 16384 + q4 * 4096 + t * 16); } }
    s8v aA[4], aB[4];
#define LOADA(S, KT)                                                      \
    { _Pragma("unroll") for (int ks = 0; ks < 4; ++ks) {                  \
        a##S[ks] = *(const s8v*)(pA + (KT) * 2048 + ks * 512); } }
#define MFMAX(S, KT)                                                                        \
    { const char* bbq = smem + ((KT) & 3) * 4096;                                           \
      _Pragma("unroll") for (int ks = 0; ks < 4; ++ks) {                                    \
        s8v b0 = *(const s8v*)(bbq + ks * 1024 + lane * 16);                                \
        s8v b1 = *(const s8v*)(bbq + 16384 + ks * 1024 + lane * 16);                        \
        acc0 = __builtin_amdgcn_mfma_f32_32x32x16_bf16(a##S[ks], b0, acc0, 0, 0, 0);        \
        acc1 = __builtin_amdgcn_mfma_f32_32x32x16_bf16(a##S[ks], b1, acc1, 0, 0, 0); } }
    STAGEB(0)
    LOADA(A, 0)
    asm volatile("s_waitcnt vmcnt(0)" ::: "memory");
    __syncthreads();
    LOADA(B, 1)
    __builtin_amdgcn_sched_barrier(0);
    MFMAX(A, 0)
    LOADA(A, 2)
    __builtin_amdgcn_sched_barrier(0);
    MFMAX(B, 1)
    LOADA(B, 3)
    __builtin_amdgcn_sched_barrier(0);
    MFMAX(A, 2)
    LOADA(A, 4)
    __builtin_amdgcn_sched_barrier(0);
    MFMAX(B, 3)
    __syncthreads();                 // all waves done reading phase-0 B
    STAGEB(1)
    asm volatile("s_waitcnt vmcnt(0)" ::: "memory");
    __syncthreads();
    LOADA(B, 5)
    __builtin_amdgcn_sched_barrier(0);
    MFMAX(A, 4)
    LOADA(A, 6)
    __builtin_amdgcn_sched_barrier(0);
    MFMAX(B, 5)
    LOADA(B, 7)
    __builtin_amdgcn_sched_barrier(0);
    MFMAX(A, 6)
    __builtin_amdgcn_sched_barrier(0);
    MFMAX(B, 7)
#undef LOADA
#undef MFMAX
#undef STAGEB
    __syncthreads();                     // B LDS dead; safe to alias vbuf below

    float* vbuf = (float*)smem;          // [64][129] f32
    const int proj = c0 >> 9;
    if (proj < 2) {
        const float* ct = tab + (proj ? 2 * LQ * HALF : 0);
        const float* st = tab + (proj ? 3 * LQ * HALF : LQ * HALF);
        u16* oh = proj ? kh : qh;
        const int hh = (c0 & 511) >> 6;
        float lgf = 0.f;
        if (proj == 1) {
            double lg = -3.4657359027997265 + (double)hh * (-2.772588722239781 / 7.0);
            lgf = (float)(log(1.0 - exp(lg)) * 1.4426950408889634);
        }
#pragma unroll
        for (int n = 0; n < 2; ++n) {
            const f16v acc = n ? acc1 : acc0;
            int C = c0 + n * 32 + c31;
            int hs = C & 63, i2 = hs >> 1;
            float sgn = (hs & 1) ? 1.f : -1.f;
#pragma unroll
            for (int r = 0; r < 16; ++r) {
                int lrow = wv * 32 + (r & 3) + 8 * (r >> 2) + 4 * hi;
                int pos = l0 + lrow;
                float val = acc[r];
                float part = __shfl_xor(val, 1);
                float res = val * ct[pos * HALF + i2] + sgn * part * st[pos * HALF + i2];
                size_t o = ((size_t)hh * LQ + pos) * HS + hs;
                oh[o] = f2bf(res);
                if (proj == 1) {
                    float wf = exp2f(lgf * (float)(64 - (pos & 63)));   // gamma^(64-m')
                    vbuf[(n * 32 + c31) * 129 + lrow] = res * wf;
                }
            }
        }
        if (proj == 1) {
            __syncthreads();
            int cl = t >> 2, lseg = (t & 3) * 32;
            size_t o = ((size_t)hh * HS + cl) * LQ + l0 + lseg;
#pragma unroll
            for (int ch4 = 0; ch4 < 4; ++ch4) {
                s8v pkh;
#pragma unroll
                for (int j = 0; j < 8; ++j) pkh[j] = (short)f2bf(vbuf[cl * 129 + lseg + ch4 * 8 + j]);
                *(s8v*)(ktw + o + ch4 * 8) = pkh;
            }
        }
    } else if (proj == 2) {
#pragma unroll
        for (int n = 0; n < 2; ++n) {
            const f16v acc = n ? acc1 : acc0;
            int cl = n * 32 + c31;
#pragma unroll
            for (int r = 0; r < 16; ++r) {
                int lrow = wv * 32 + (r & 3) + 8 * (r >> 2) + 4 * hi;
                vbuf[cl * 129 + lrow] = acc[r];
            }
        }
        __syncthreads();
        int h = (c0 & 511) >> 6;
        int cl = t >> 2, lseg = (t & 3) * 32;
        size_t o = ((size_t)h * HS + cl) * LQ + l0 + lseg;
#pragma unroll
        for (int ch = 0; ch < 4; ++ch) {
            s8v pk;
#pragma unroll
            for (int j = 0; j < 8; ++j) pk[j] = (short)f2bf(vbuf[cl * 129 + lseg + ch * 8 + j]);
            *(s8v*)(vt + o + ch * 8) = pk;
        }
    } else {
#pragma unroll
        for (int n = 0; n < 2; ++n) {
            const f16v acc = n ? acc1 : acc0;
            int C = (c0 & 511) + n * 32 + c31;
#pragma unroll
            for (int r = 0; r < 16; ++r) {
                int lrow = wv * 32 + (r & 3) + 8 * (r >> 2) + 4 * hi;
                float vv = acc[r];
                gate16[(size_t)(l0 + lrow) * DD + C] = f2bf(vv / (1.f + expf(-vv)));
            }
        }
    }
}

// ---------------- pass1: per-chunk state A^T[ch][d] (bf16 out), 4 waves/chunk ----------------
__global__ __launch_bounds__(256) void k_ret1(
    const u16* __restrict__ vt, const u16* __restrict__ ktw,
    u16* __restrict__ A) {
    const int t = threadIdx.x;
    const int c = blockIdx.x;
    const int h = blockIdx.y;
    const int wv = t >> 6, lane = t & 63, c31 = lane & 31, hi = lane >> 5;
    const int wch = wv >> 1, wd = wv & 1;

    s8v va[4];
    const u16* vp = vt + ((size_t)h * 64 + wch * 32 + c31) * LQ + c * 64 + hi * 8;
#pragma unroll
    for (int ks = 0; ks < 4; ++ks) va[ks] = *(const s8v*)(vp + ks * 16);

    f16v a;
#pragma unroll
    for (int i = 0; i < 16; ++i) a[i] = 0.f;

    const size_t kbase = ((size_t)h * 64 + wd * 32 + c31) * LQ + c * 64 + hi * 8;
#pragma unroll
    for (int ks = 0; ks < 4; ++ks) {
        s8v b_h = *(const s8v*)(ktw + kbase + ks * 16);
        a = __builtin_amdgcn_mfma_f32_32x32x16_bf16(va[ks], b_h, a, 0, 0, 0);
    }

    u16* Ab = A + ((size_t)h * 64 + c) * 4096;
#pragma unroll
    for (int r = 0; r < 16; ++r) {
        int ch = wch * 32 + (r & 3) + 8 * (r >> 2) + 4 * hi;
        Ab[ch * 64 + wd * 32 + c31] = f2bf(a[r]);
    }
}

// ---------------- pass2: weighted prefix scan over chunks (bf16 in) -> S^T bf16 ----------------
__global__ __launch_bounds__(256) void k_scan(
    const u16* __restrict__ A, u16* __restrict__ sth) {
    const int bx = blockIdx.x;
    const int h = bx >> 4;
    const int e = (bx & 15) * 256 + threadIdx.x;
    double lg = -3.4657359027997265 + (double)h * (-2.772588722239781 / 7.0);
    double gamma = 1.0 - exp(lg);
    float g64 = (float)pow(gamma, 64.0);
    const u16* Ab = A + (size_t)h * 64 * 4096 + e;
    u16* shb = sth + (size_t)h * 64 * 4096 + e;
    float av[64];
#pragma unroll
    for (int cc = 0; cc < 64; ++cc) av[cc] = bf2f(Ab[(size_t)cc * 4096]);
    float s = 0.f;
#pragma unroll
    for (int cc = 0; cc < 64; ++cc) {
        if (cc) shb[(size_t)cc * 4096] = f2bf(s);
        s = fmaf(g64, s, av[cc]);
    }
}

// ---------------- pass3: retention chunk + fused GroupNorm*gate -> frag-packed gg ----------------
// grid (64, 8), block 256 (4 waves). wave = (ws = row strip, wc = output col half).
__global__ __launch_bounds__(256) void k_ret3(
    const u16* __restrict__ qh, const u16* __restrict__ kh,
    const u16* __restrict__ vt, const u16* __restrict__ sth,
    const u16* __restrict__ gate16,
    const float* __restrict__ gw, const float* __restrict__ gb,
    u16* __restrict__ Gf) {
    __shared__ __align__(16) char sBuf[16640];   // KH 8K | VT 8K; later gT[64][65] f32
    __shared__ float stats[64][2][2];            // [row][wc][s,ss]
    const int t = threadIdx.x;
    const int c = blockIdx.x;
    const int h = blockIdx.y;
    const int wv = t >> 6, lane = t & 63, c31 = lane & 31, hi = lane >> 5;
    const int ws = wv >> 1, wc = wv & 1;
    const int l0q = c * 64;

    double lg = -3.4657359027997265 + (double)h * (-2.772588722239781 / 7.0);
    double gamma = 1.0 - exp(lg);
    float lgf = (float)(log(gamma) * 1.4426950408889634);
    float c1a[4], c8a[4];
#pragma unroll
    for (int m = 0; m < 4; ++m) { c1a[m] = exp2f(-lgf * (float)m); c8a[m] = exp2f(-lgf * (float)(8 * m)); }

    // Q fragments for this wave's row strip
    s8v qhf[4];
    {
        const u16* qph = qh + ((size_t)h * LQ + l0q + ws * 32 + c31) * HS + hi * 8;
#pragma unroll
        for (int ks = 0; ks < 4; ++ks) qhf[ks] = *(const s8v*)(qph + ks * 16);
    }

    // stage K + VT (pre-swizzled source, linear LDS dest), 4 x 16B per thread
    {
        const char* gKH = (const char*)kh + ((size_t)h * LQ + l0q) * 128;
        const char* gVT = (const char*)vt + ((size_t)h * 64) * 8192 + l0q * 2;
#pragma unroll
        for (int i_ = 0; i_ < 4; ++i_) {
            int boff = i_ * 4096 + t * 16;
            int seg = boff >> 13;
            int o_ = boff & 8191;
            int osrc = o_ ^ (((o_ >> 7) & 7) << 4);
            const char* src = (seg == 0) ? gKH + osrc
                            : gVT + (size_t)(osrc >> 7) * 8192 + (osrc & 127);
            gld16(sBuf + i_ * 4096 + (t >> 6) * 1024, src);
        }
    }

    // inter-chunk: qs = Q @ S^T for this wave's col half
    f16v qs;
#pragma unroll
    for (int i = 0; i < 16; ++i) qs[i] = 0.f;
    if (c > 0) {
        const u16* sbh = sth + ((size_t)h * 64 + c) * 4096;
#pragma unroll
        for (int ks = 0; ks < 4; ++ks) {
            int off = (wc * 32 + c31) * 64 + ks * 16 + hi * 8;
            s8v b_h = *(const s8v*)(sbh + off);
            qs = __builtin_amdgcn_mfma_f32_32x32x16_bf16(qhf[ks], b_h, qs, 0, 0, 0);
        }
    }

    asm volatile("s_waitcnt vmcnt(0)" ::: "memory");
    __syncthreads();

    // intra-chunk masked tile (QK^T duplicated across wc; PV split by wc)
    f16v acc;
#pragma unroll
    for (int i = 0; i < 16; ++i) acc[i] = 0.f;
    const char* bKH = sBuf;
    const char* bVT = sBuf + 8192;

#pragma unroll
    for (int jt = 0; jt < 2; ++jt) {
        if (ws == 0 && jt == 1) break;
        f16v sacc;
#pragma unroll
        for (int i = 0; i < 16; ++i) sacc[i] = 0.f;
#pragma unroll
        for (int ks = 0; ks < 4; ++ks) {
            int krow = jt * 32 + c31;
            int ph = krow * 128 + ((ks * 32 + hi * 16) ^ ((krow & 7) << 4));
            s8v ah = *(const s8v*)(bKH + ph);
            sacc = __builtin_amdgcn_mfma_f32_32x32x16_bf16(ah, qhf[ks], sacc, 0, 0, 0);
        }
        const int D0 = (ws * 32 + c31) - jt * 32;
        float base = exp2f(lgf * (float)(D0 - 4 * hi));
        u32 w[8];
#pragma unroll
        for (int g = 0; g < 4; ++g) {
            float wg = base * c8a[g];
            float v0 = sacc[4 * g + 0] * (wg * c1a[0]);
            float v1 = sacc[4 * g + 1] * (wg * c1a[1]);
            float v2 = sacc[4 * g + 2] * (wg * c1a[2]);
            float v3 = sacc[4 * g + 3] * (wg * c1a[3]);
            int jr = 8 * g + 4 * hi;
            if (D0 - (jr + 0) < 0) v0 = 0.f;
            if (D0 - (jr + 1) < 0) v1 = 0.f;
            if (D0 - (jr + 2) < 0) v2 = 0.f;
            if (D0 - (jr + 3) < 0) v3 = 0.f;
            w[2 * g]     = (u32)f2bf(v0) | ((u32)f2bf(v1) << 16);
            w[2 * g + 1] = (u32)f2bf(v2) | ((u32)f2bf(v3) << 16);
        }
        u32 e0 = __shfl_xor(hi ? w[0] : w[2], 32);
        u32 e1 = __shfl_xor(hi ? w[1] : w[3], 32);
        u32 e2 = __shfl_xor(hi ? w[4] : w[6], 32);
        u32 e3 = __shfl_xor(hi ? w[5] : w[7], 32);
        u32x4 a0v = { hi ? e0 : w[0], hi ? e1 : w[1], hi ? w[2] : e0, hi ? w[3] : e1 };
        u32x4 a1v = { hi ? e2 : w[4], hi ? e3 : w[5], hi ? w[6] : e2, hi ? w[7] : e3 };
        s8v af0 = __builtin_bit_cast(s8v, a0v);
        s8v af1 = __builtin_bit_cast(s8v, a1v);
#pragma unroll
        for (int ksl = 0; ksl < 2; ++ksl) {
            s8v af = ksl ? af1 : af0;
            int cb = (jt * 2 + ksl) * 32 + hi * 16;
            int rv = wc * 32 + c31;
            s8v vb = *(const s8v*)(bVT + rv * 128 + (cb ^ ((rv & 7) << 4)));
            acc = __builtin_amdgcn_mfma_f32_32x32x16_bf16(af, vb, acc, 0, 0, 0);
        }
    }

    // epilogue: combine inter+intra; cross-wc GroupNorm stats via LDS; *gate; frag-pack gg
    float vv[16];
#pragma unroll
    for (int r = 0; r < 16; ++r) {
        int row = (r & 3) + 8 * (r >> 2) + 4 * hi;
        int nloc = ws * 32 + row;
        float sc = exp2f(lgf * (float)nloc);
        vv[r] = acc[r] + sc * qs[r];
    }
#pragma unroll
    for (int r = 0; r < 16; ++r) {
        float s = vv[r], ss = vv[r] * vv[r];
#pragma unroll
        for (int off = 1; off < 32; off <<= 1) {
            s  += __shfl_xor(s, off);
            ss += __shfl_xor(ss, off);
        }
        if (c31 == 0) {
            int nloc = ws * 32 + (r & 3) + 8 * (r >> 2) + 4 * hi;
            stats[nloc][wc][0] = s;
            stats[nloc][wc][1] = ss;
        }
    }
    __syncthreads();   // stats ready; all sBuf (K/V) reads also done -> safe to alias gT

    float* gT = (float*)sBuf;           // [64][65] f32
    const float gwv = gw[h * HS + wc * 32 + c31];
    const float gbv = gb[h * HS + wc * 32 + c31];
#pragma unroll
    for (int r = 0; r < 16; ++r) {
        int nloc = ws * 32 + (r & 3) + 8 * (r >> 2) + 4 * hi;
        float s  = stats[nloc][0][0] + stats[nloc][1][0];
        float ss = stats[nloc][0][1] + stats[nloc][1][1];
        float mean = s * (1.f / 64.f);
        float var = ss * (1.f / 64.f) - mean * mean;
        float inv = rsqrtf(var + 1e-5f);
        size_t o = (size_t)(l0q + nloc) * DD + h * HS + wc * 32 + c31;
        float g = ((vv[r] - mean) * inv * gwv + gbv) * bf2f(gate16[o]);
        gT[nloc * 65 + wc * 32 + c31] = g;
    }
    __syncthreads();
#pragma unroll
    for (int i = 0; i < 2; ++i) {
        int u = t + i * 256;            // 0..511
        int rbl = u >> 8;
        int ks = (u >> 6) & 3;
        int ln = u & 63;
        int row = rbl * 32 + (ln & 31);
        int ch = ks * 16 + (ln >> 5) * 8;
        s8v pk;
#pragma unroll
        for (int j = 0; j < 8; ++j) pk[j] = (short)f2bf(gT[row * 65 + ch + j]);
        size_t off = ((((size_t)(c * 2 + rbl) * 8 + h) * 4 + ks) * 64 + ln) * 8;
        *(s8v*)(Gf + off) = pk;
    }
}

// ---------------- out = gg @ W_O (A frag-direct pinned, B LDS-shared 2 phases) [R10] ----------------
__global__ __launch_bounds__(256) void k_out(
    const u16* __restrict__ Gf, const u16* __restrict__ Wf,
    float* __restrict__ out) {
    __shared__ __align__(16) char smem[32768];
    const int t = threadIdx.x;
    const int l0 = blockIdx.x * 128;
    const int c0 = blockIdx.y * 64;
    const int wv = t >> 6;
    const int lane = t & 63;
    const int c31 = lane & 31;
    const int hi = lane >> 5;

    const int rb = blockIdx.x * 4 + wv;
    const u16* pA  = Gf + (size_t)rb * 16384 + lane * 8;
    const char* gB = (const char*)(Wf + (size_t)(64 + blockIdx.y * 2) * 16384);

    f16v acc0, acc1;
#pragma unroll
    for (int i = 0; i < 16; ++i) { acc0[i] = 0.f; acc1[i] = 0.f; }

#define STAGEB(PH)                                                             \
    { _Pragma("unroll") for (int j = 0; j < 8; ++j) {                          \
        int seg = j >> 2, q4 = j & 3;                                          \
        gld16(smem + seg * 16384 + q4 * 4096 + wv * 1024,                      \
              gB + seg * 32768 + (PH) * 16384 + q4 * 4096 + t * 16); } }
    s8v aA[4], aB[4];
#define LOADO(S, KT)                                                      \
    { _Pragma("unroll") for (int ks = 0; ks < 4; ++ks) {                  \
        a##S[ks] = *(const s8v*)(pA + (KT) * 2048 + ks * 512); } }
#define MFMAO(S, KT)                                                                        \
    { const char* bbq = smem + ((KT) & 3) * 4096;                                           \
      _Pragma("unroll") for (int ks = 0; ks < 4; ++ks) {                                    \
        s8v b0 = *(const s8v*)(bbq + ks * 1024 + lane * 16);                                \
        s8v b1 = *(const s8v*)(bbq + 16384 + ks * 1024 + lane * 16);                        \
        acc0 = __builtin_amdgcn_mfma_f32_32x32x16_bf16(a##S[ks], b0, acc0, 0, 0, 0);        \
        acc1 = __builtin_amdgcn_mfma_f32_32x32x16_bf16(a##S[ks], b1, acc1, 0, 0, 0); } }
    STAGEB(0)
    LOADO(A, 0)
    asm volatile("s_waitcnt vmcnt(0)" ::: "memory");
    __syncthreads();
    LOADO(B, 1)
    __builtin_amdgcn_sched_barrier(0);
    MFMAO(A, 0)
    LOADO(A, 2)
    __builtin_amdgcn_sched_barrier(0);
    MFMAO(B, 1)
    LOADO(B, 3)
    __builtin_amdgcn_sched_barrier(0);
    MFMAO(A, 2)
    LOADO(A, 4)
    __builtin_amdgcn_sched_barrier(0);
    MFMAO(B, 3)
    __syncthreads();
    STAGEB(1)
    asm volatile("s_waitcnt vmcnt(0)" ::: "memory");
    __syncthreads();
    LOADO(B, 5)
    __builtin_amdgcn_sched_barrier(0);
    MFMAO(A, 4)
    LOADO(A, 6)
    __builtin_amdgcn_sched_barrier(0);
    MFMAO(B, 5)
    LOADO(B, 7)
    __builtin_amdgcn_sched_barrier(0);
    MFMAO(A, 6)
    __builtin_amdgcn_sched_barrier(0);
    MFMAO(B, 7)
#undef LOADO
#undef MFMAO
#undef STAGEB

#pragma unroll
    for (int n = 0; n < 2; ++n) {
        const f16v acc = n ? acc1 : acc0;
        int C = c0 + n * 32 + c31;
#pragma unroll
        for (int r = 0; r < 16; ++r) {
            int lrow = wv * 32 + (r & 3) + 8 * (r >> 2) + 4 * hi;
            out[(size_t)(l0 + lrow) * DD + C] = acc[r];
        }
    }
}

extern "C" void kernel_launch(void* const* d_in, const int* in_sizes, int n_in,
                              void* d_out, int out_size, void* d_ws, size_t ws_size,
                              hipStream_t stream) {
    const float* X   = (const float*)d_in[0];
    const float* W_Q = (const float*)d_in[1];
    const float* W_K = (const float*)d_in[2];
    const float* W_V = (const float*)d_in[3];
    const float* W_G = (const float*)d_in[4];
    const float* W_O = (const float*)d_in[5];
    const float* gnw = (const float*)d_in[6];
    const float* gnb = (const float*)d_in[7];

    float* ws   = (float*)d_ws;
    u16* qhp  = (u16*)(ws + WS_QH);
    u16* khp  = (u16*)(ws + WS_KH);
    u16* vtp  = (u16*)(ws + WS_VT);
    u16* xfp  = (u16*)(ws + WS_XFH);
    u16* wf   = (u16*)(ws + WS_WF);
    u16* gate16 = (u16*)(ws + WS_GATE);
    float* tab  = ws + WS_TAB;
    u16* ktwp = (u16*)(ws + WS_KTWH);
    u16* Abuf = (u16*)(ws + WS_XFH);   // A_state (bf16) over dead Xf
    u16* sthp = (u16*)(ws + WS_KTWH);  // St over dead ktw
    u16* Gfp  = (u16*)(ws + WS_XFL);   // frag-packed gg over unused XFL region (A dead by then too)
    float* out  = (float*)d_out;

    k_pre<<<2816, 256, 0, stream>>>(X, W_Q, W_K, W_V, W_G, W_O, tab, xfp, wf);
    k_fused<<<1024, 256, 0, stream>>>(xfp, wf, tab, qhp, khp, vtp, gate16, ktwp);
    k_ret1<<<dim3(64, 8), 256, 0, stream>>>(vtp, ktwp, Abuf);
    k_scan<<<128, 256, 0, stream>>>(Abuf, sthp);
    k_ret3<<<dim3(64, 8), 256, 0, stream>>>(qhp, khp, vtp, sthp, gate16, gnw, gnb, Gfp);
    k_out<<<dim3(32, 8), 256, 0, stream>>>(Gfp, wf, out);
}